// Round 3
// baseline (450.748 us; speedup 1.0000x reference)
//
#include <hip/hip_runtime.h>

typedef __bf16 bf16_t;
typedef __bf16 bf16x8 __attribute__((ext_vector_type(8)));
typedef __bf16 bf16x4 __attribute__((ext_vector_type(4)));
typedef float f32x4 __attribute__((ext_vector_type(4)));

#define MFMA16(a, b, c) __builtin_amdgcn_mfma_f32_16x16x32_bf16(a, b, c, 0, 0, 0)

__device__ __forceinline__ void g2l16(const void* g, void* l) {
  __builtin_amdgcn_global_load_lds(
      (__attribute__((address_space(1))) void*)g,
      (__attribute__((address_space(3))) void*)l, 16, 0, 0);
}

// ---------------- fp32 -> bf16 conversion ----------------
__global__ void cvt_f32_bf16(const float* __restrict__ in, bf16_t* __restrict__ out, int n4) {
  int i = blockIdx.x * blockDim.x + threadIdx.x;
  if (i >= n4) return;
  const float4 v = ((const float4*)in)[i];
  bf16x4 o;
  o[0] = (bf16_t)v.x; o[1] = (bf16_t)v.y; o[2] = (bf16_t)v.z; o[3] = (bf16_t)v.w;
  ((bf16x4*)out)[i] = o;
}

// ---------------- bias permute: rel[h][q][k] f32 -> relp[h][q][kb][lr][jt] bf16 ----------------
// k = kb*128 + jt*16 + lr. Pre-scaled by log2e. Lets each attn wave-row load
// its 8 bias values (jt=0..7) as ONE bf16x8 16B vector load instead of 8
// scalar fp32 gathers.
__global__ void permute_rel(const float* __restrict__ rel, bf16_t* __restrict__ relp) {
  __shared__ float row[1024];
  const size_t base = (size_t)blockIdx.x * 1024;  // blockIdx.x = h*1024 + q
  const int t = threadIdx.x;
  *(float4*)(row + t * 4) = *(const float4*)(rel + base + t * 4);
  __syncthreads();
  const float LOG2E = 1.44269504f;
  const int o0 = t * 4;
  bf16x4 v;
#pragma unroll
  for (int j = 0; j < 4; ++j) {
    const int o = o0 + j;
    const int kb = o >> 7, rem = o & 127;
    const int lr = rem >> 3, jt = rem & 7;
    v[j] = (bf16_t)(row[kb * 128 + jt * 16 + lr] * LOG2E);
  }
  *(bf16x4*)(relp + base + o0) = v;
}

// ---------------- V transpose: [bh][seq][32] -> [bh][32][seq] ----------------
__global__ void transpose_v(const bf16_t* __restrict__ Vb, bf16_t* __restrict__ Vtb) {
  __shared__ bf16_t T[64][40];
  const int bh = blockIdx.y, s0 = blockIdx.x * 64;
  const int r = threadIdx.x >> 2, c8 = (threadIdx.x & 3) * 8;
  const bf16x8 v = *(const bf16x8*)(Vb + ((size_t)bh * 1024 + s0 + r) * 32 + c8);
#pragma unroll
  for (int j = 0; j < 8; ++j) T[r][c8 + j] = v[j];
  __syncthreads();
  const int d = threadIdx.x >> 3, q8 = (threadIdx.x & 7) * 8;
  bf16x8 o;
#pragma unroll
  for (int j = 0; j < 8; ++j) o[j] = T[q8 + j][d];
  *(bf16x8*)(Vtb + ((size_t)bh * 32 + d) * 1024 + s0 + q8) = o;
}

// ---------------- NT GEMM: C[m][n] = sum_k A[m][k] * B[n][k]  ----------------
// MODE 0: A row-major [M][K]; epilogue scatters to Q(scaled)/K/V bf16.
// MODE 1: A is head-major [B*24][1024][32] (attention O); fp32 C store.
template <int MODE>
__global__ __launch_bounds__(256, 2) void gemm_bt(
    const bf16_t* __restrict__ A, const bf16_t* __restrict__ Bw,
    const float* __restrict__ bias, float* __restrict__ Cout,
    bf16_t* __restrict__ Qb, bf16_t* __restrict__ Kb, bf16_t* __restrict__ Vb,
    int M, int N, int K) {
  __shared__ bf16_t As[128 * 32];
  __shared__ bf16_t Bs[128 * 32];
  const int tid = threadIdx.x;
  const int wave = tid >> 6, lane = tid & 63, quad = lane >> 4, lr = lane & 15;
  const int bm = blockIdx.x * 128, bn = blockIdx.y * 128;
  const int wm = (wave >> 1) * 64, wn = (wave & 1) * 64;

  f32x4 acc[4][4] = {};

  const bf16_t* Ag;
  size_t strideA64;  // address delta for +64 rows
  if (MODE == 0) {
    Ag = A + (size_t)(bm + (tid >> 2)) * K + (tid & 3) * 8;
    strideA64 = (size_t)64 * K;
  } else {
    const int rr = bm + (tid >> 2);
    const int bidx = rr >> 10, seq = rr & 1023;
    Ag = A + ((size_t)bidx * 24 * 1024 + seq) * 32 + (tid & 3) * 8;
    strideA64 = (size_t)64 * 32;  // +64 seq rows, same batch
  }
  const bf16_t* Bg = Bw + (size_t)(bn + (tid >> 2)) * K + (tid & 3) * 8;
  bf16_t* As0 = As + tid * 8;
  bf16_t* Bs0 = Bs + tid * 8;
  const size_t strideB64 = (size_t)64 * K;

  for (int k0 = 0; k0 < K; k0 += 32) {
    const size_t aoff = (MODE == 0) ? (size_t)k0 : (size_t)(k0 >> 5) * 32768;
    __syncthreads();
    g2l16(Ag + aoff, As0);
    g2l16(Ag + strideA64 + aoff, As0 + 2048);
    g2l16(Bg + k0, Bs0);
    g2l16(Bg + strideB64 + k0, Bs0 + 2048);
    __syncthreads();
    bf16x8 af[4], bfr[4];
#pragma unroll
    for (int i = 0; i < 4; ++i)
      af[i] = *(const bf16x8*)(As + (wm + i * 16 + lr) * 32 + quad * 8);
#pragma unroll
    for (int j = 0; j < 4; ++j)
      bfr[j] = *(const bf16x8*)(Bs + (wn + j * 16 + lr) * 32 + quad * 8);
#pragma unroll
    for (int i = 0; i < 4; ++i)
#pragma unroll
      for (int j = 0; j < 4; ++j)
        acc[i][j] = MFMA16(af[i], bfr[j], acc[i][j]);
  }

#pragma unroll
  for (int i = 0; i < 4; ++i) {
    const int row = bm + wm + i * 16 + quad * 4;
#pragma unroll
    for (int j = 0; j < 4; ++j) {
      const int col = bn + wn + j * 16 + lr;
      const float bb = bias[col];
#pragma unroll
      for (int r = 0; r < 4; ++r) {
        const float v = acc[i][j][r] + bb;
        const int rr = row + r;
        if (MODE == 1) {
          Cout[(size_t)rr * N + col] = v;
        } else {
          const int b = rr >> 10, seq = rr & 1023;
          const int head = col / 96, w = col % 96;
          const int bh = b * 24 + head;
          if (w < 32) {
            Qb[((size_t)bh * 1024 + seq) * 32 + w] = (bf16_t)(v * 0.17677669529663687f);
          } else if (w < 64) {
            Kb[((size_t)bh * 1024 + seq) * 32 + (w - 32)] = (bf16_t)v;
          } else {
            Vb[((size_t)bh * 1024 + seq) * 32 + (w - 64)] = (bf16_t)v;
          }
        }
      }
    }
  }
}

// ---------------- flash attention v10 ----------------
// R2 counters: MfmaUtil 6.5 / VALUBusy 39 / HBM 8.5 / Occ 43 -> still
// latency-bound at 3.4 waves/SIMD. Two levers:
//  (a) __launch_bounds__(256,6): VGPR budget 85 > natural 60 -> no spill
//      (R1's (256,8) forced 64-budget -> spilled; this is the right dose).
//  (b) row-sum l = P*ones via MFMA (pf already loaded for PV) -> removes
//      32 v_add + 16 ds_bpermute per body from the busiest pipe (VALU),
//      adds 4 MFMA to the idlest (6.5%). Accumulates across whole kernel.
// (XCD swizzle unchanged: 16 q-tiles of one (b,h) adjacent on one XCD.)
__global__ __launch_bounds__(256, 6) void attn_flash(
    const bf16_t* __restrict__ Qb, const bf16_t* __restrict__ Kb,
    const bf16_t* __restrict__ Vtb, const bf16_t* __restrict__ relp,
    bf16_t* __restrict__ Ob) {
  __shared__ bf16_t Ps[4][16 * 132];

  const int tid = threadIdx.x;
  const int wave = tid >> 6, lane = tid & 63, quad = lane >> 4, lr = lane & 15;

  const int flat = blockIdx.x;
  const int xcd = flat & 7, slot = flat >> 3;
  const int pair = xcd + 8 * (slot >> 4);   // 0..191; same pair -> same XCD
  const int qi = slot & 15;
  const int b = pair / 24, h = pair % 24;
  const int bh = b * 24 + h;
  const int q0 = qi * 64 + wave * 16;
  const float LOG2E = 1.44269504f;

  const bf16x8 qf = *(const bf16x8*)(Qb + ((size_t)bh * 1024 + q0 + lr) * 32 + quad * 8);

  bf16x8 onesf;
#pragma unroll
  for (int i = 0; i < 8; ++i) onesf[i] = (bf16_t)1.0f;

  f32x4 o_acc[2] = {};
  f32x4 l_acc = {};  // row-sum accumulator: l = P * ones, same layout as o_acc

  // permuted bias: relp[((h*1024+q)*8 + kb)*128 + lr*8 + jt], k = kb*128+jt*16+lr
  const bf16_t* relg = relp + ((size_t)h * 1024 + q0 + quad * 4) * 1024 + lr * 8;
  const bf16_t* Kg = Kb + (size_t)bh * 1024 * 32;
  const bf16_t* Vg = Vtb + (size_t)bh * 32 * 1024;
  bf16_t* Pw = &Ps[wave][0];

  auto body = [&](int kt) {
    // bias tile: one bf16x8 per acc row (already scaled by log2e)
    bf16x8 bw[4];
    const bf16_t* rb = relg + kt;  // kt multiple of 128: (kt>>7)*128 == kt
#pragma unroll
    for (int r = 0; r < 4; ++r) bw[r] = *(const bf16x8*)(rb + (size_t)r * 1024);

    const bf16_t* Kbase = Kg + (size_t)kt * 32;
    const bf16_t* Vbase = Vg + kt;

    // S = Q K^T (C-layout: row = quad*4+r, col = jt*16+lr)
    f32x4 s[8];
    const f32x4 zz = {0.f, 0.f, 0.f, 0.f};
#pragma unroll
    for (int jt = 0; jt < 8; ++jt) {
      const bf16x8 kf = *(const bf16x8*)(Kbase + (size_t)(jt * 16 + lr) * 32 + quad * 8);
      s[jt] = MFMA16(qf, kf, zz);
    }
    // P = exp2(S*log2e + bias_prescaled) — no max subtraction needed
#pragma unroll
    for (int jt = 0; jt < 8; ++jt)
#pragma unroll
      for (int r = 0; r < 4; ++r)
        s[jt][r] = exp2f(fmaf(s[jt][r], LOG2E, (float)bw[r][jt]));

    // P -> LDS (C-layout to A-layout transform), per-wave region
#pragma unroll
    for (int jt = 0; jt < 8; ++jt)
#pragma unroll
      for (int r = 0; r < 4; ++r)
        Pw[(quad * 4 + r) * 132 + jt * 16 + lr] = (bf16_t)s[jt][r];

    // O += P V ; l += P * ones (row-sum on the idle MFMA pipe)
#pragma unroll
    for (int ks = 0; ks < 4; ++ks) {
      const bf16x8 pf = *(const bf16x8*)(Pw + lr * 132 + ks * 32 + quad * 8);
      l_acc = MFMA16(pf, onesf, l_acc);
#pragma unroll
      for (int nt = 0; nt < 2; ++nt) {
        const bf16x8 vf = *(const bf16x8*)(Vbase + (size_t)(nt * 16 + lr) * 1024 + ks * 32 + quad * 8);
        o_acc[nt] = MFMA16(pf, vf, o_acc[nt]);
      }
    }
  };

  for (int kt = 0; kt < 1024; kt += 256) {
    body(kt);
    body(kt + 128);
  }

  // write O head-major [bh][seq][32] — packed stores
  float inv_l[4];
#pragma unroll
  for (int r = 0; r < 4; ++r) inv_l[r] = 1.0f / l_acc[r];
#pragma unroll
  for (int nt = 0; nt < 2; ++nt)
#pragma unroll
    for (int r = 0; r < 4; ++r) {
      const int seq = q0 + quad * 4 + r;
      Ob[((size_t)bh * 1024 + seq) * 32 + nt * 16 + lr] = (bf16_t)(o_acc[nt][r] * inv_l[r]);
    }
}

extern "C" void kernel_launch(void* const* d_in, const int* in_sizes, int n_in,
                              void* d_out, int out_size, void* d_ws, size_t ws_size,
                              hipStream_t stream) {
  const float* x = (const float*)d_in[0];
  const float* rel = (const float*)d_in[1];
  const float* Wqkv = (const float*)d_in[2];
  const float* bqkv = (const float*)d_in[3];
  const float* Wproj = (const float*)d_in[4];
  const float* bproj = (const float*)d_in[5];
  float* out = (float*)d_out;

  char* ws = (char*)d_ws;
  bf16_t* xb = (bf16_t*)ws;     ws += (size_t)8192 * 768 * 2;
  bf16_t* wqkvb = (bf16_t*)ws;  ws += (size_t)2304 * 768 * 2;
  bf16_t* wprojb = (bf16_t*)ws; ws += (size_t)768 * 768 * 2;
  bf16_t* Qb = (bf16_t*)ws;     ws += (size_t)192 * 1024 * 32 * 2;
  bf16_t* Kb = (bf16_t*)ws;     ws += (size_t)192 * 1024 * 32 * 2;
  bf16_t* Vb = (bf16_t*)ws;     ws += (size_t)192 * 1024 * 32 * 2;
  bf16_t* Vtb = (bf16_t*)ws;    ws += (size_t)192 * 1024 * 32 * 2;
  bf16_t* relp = (bf16_t*)ws;   ws += (size_t)24 * 1024 * 1024 * 2;
  bf16_t* Ob = xb;  // xb dead after QKV GEMM; O is head-major [bh][seq][32]

  cvt_f32_bf16<<<(8192 * 768 / 4 + 255) / 256, 256, 0, stream>>>(x, xb, 8192 * 768 / 4);
  cvt_f32_bf16<<<(2304 * 768 / 4 + 255) / 256, 256, 0, stream>>>(Wqkv, wqkvb, 2304 * 768 / 4);
  cvt_f32_bf16<<<(768 * 768 / 4 + 255) / 256, 256, 0, stream>>>(Wproj, wprojb, 768 * 768 / 4);
  permute_rel<<<dim3(24 * 1024), 256, 0, stream>>>(rel, relp);

  gemm_bt<0><<<dim3(64, 18), 256, 0, stream>>>(xb, wqkvb, bqkv, nullptr,
                                               Qb, Kb, Vb, 8192, 2304, 768);
  transpose_v<<<dim3(16, 192), 256, 0, stream>>>(Vb, Vtb);
  attn_flash<<<dim3(3072), 256, 0, stream>>>(Qb, Kb, Vtb, relp, Ob);
  gemm_bt<1><<<dim3(64, 6), 256, 0, stream>>>(Ob, wprojb, bproj, out,
                                              nullptr, nullptr, nullptr, 8192, 768, 768);
}

// Round 4
// 407.038 us; speedup vs baseline: 1.1074x; 1.1074x over previous
//
#include <hip/hip_runtime.h>

typedef __bf16 bf16_t;
typedef __bf16 bf16x8 __attribute__((ext_vector_type(8)));
typedef __bf16 bf16x4 __attribute__((ext_vector_type(4)));
typedef float f32x4 __attribute__((ext_vector_type(4)));

#define MFMA16(a, b, c) __builtin_amdgcn_mfma_f32_16x16x32_bf16(a, b, c, 0, 0, 0)

#if __has_builtin(__builtin_amdgcn_exp2f)
#define EXP2(x) __builtin_amdgcn_exp2f(x)
#else
#define EXP2(x) exp2f(x)
#endif

__device__ __forceinline__ void g2l16(const void* g, void* l) {
  __builtin_amdgcn_global_load_lds(
      (__attribute__((address_space(1))) void*)g,
      (__attribute__((address_space(3))) void*)l, 16, 0, 0);
}

// ---------------- fp32 -> bf16 conversion ----------------
__global__ void cvt_f32_bf16(const float* __restrict__ in, bf16_t* __restrict__ out, int n4) {
  int i = blockIdx.x * blockDim.x + threadIdx.x;
  if (i >= n4) return;
  const float4 v = ((const float4*)in)[i];
  bf16x4 o;
  o[0] = (bf16_t)v.x; o[1] = (bf16_t)v.y; o[2] = (bf16_t)v.z; o[3] = (bf16_t)v.w;
  ((bf16x4*)out)[i] = o;
}

// ---------------- bias permute: rel[h][q][k] f32 -> relp[h][q][kb][lr][jt] bf16 ----------------
// k = kb*128 + jt*16 + lr. Pre-scaled by log2e. One bf16x8 16B load per acc row.
__global__ void permute_rel(const float* __restrict__ rel, bf16_t* __restrict__ relp) {
  __shared__ float row[1024];
  const size_t base = (size_t)blockIdx.x * 1024;  // blockIdx.x = h*1024 + q
  const int t = threadIdx.x;
  *(float4*)(row + t * 4) = *(const float4*)(rel + base + t * 4);
  __syncthreads();
  const float LOG2E = 1.44269504f;
  const int o0 = t * 4;
  bf16x4 v;
#pragma unroll
  for (int j = 0; j < 4; ++j) {
    const int o = o0 + j;
    const int kb = o >> 7, rem = o & 127;
    const int lr = rem >> 3, jt = rem & 7;
    v[j] = (bf16_t)(row[kb * 128 + jt * 16 + lr] * LOG2E);
  }
  *(bf16x4*)(relp + base + o0) = v;
}

// ---------------- V transpose: [bh][seq][32] -> [bh][32][seq] ----------------
__global__ void transpose_v(const bf16_t* __restrict__ Vb, bf16_t* __restrict__ Vtb) {
  __shared__ bf16_t T[64][40];
  const int bh = blockIdx.y, s0 = blockIdx.x * 64;
  const int r = threadIdx.x >> 2, c8 = (threadIdx.x & 3) * 8;
  const bf16x8 v = *(const bf16x8*)(Vb + ((size_t)bh * 1024 + s0 + r) * 32 + c8);
#pragma unroll
  for (int j = 0; j < 8; ++j) T[r][c8 + j] = v[j];
  __syncthreads();
  const int d = threadIdx.x >> 3, q8 = (threadIdx.x & 7) * 8;
  bf16x8 o;
#pragma unroll
  for (int j = 0; j < 8; ++j) o[j] = T[q8 + j][d];
  *(bf16x8*)(Vtb + ((size_t)bh * 32 + d) * 1024 + s0 + q8) = o;
}

// ---------------- NT GEMM: C[m][n] = sum_k A[m][k] * B[n][k]  ----------------
// MODE 0: A row-major [M][K]; epilogue scatters to Q(scaled)/K/V bf16.
// MODE 1: A is head-major [B*24][1024][32] (attention O); fp32 C store.
template <int MODE>
__global__ __launch_bounds__(256, 2) void gemm_bt(
    const bf16_t* __restrict__ A, const bf16_t* __restrict__ Bw,
    const float* __restrict__ bias, float* __restrict__ Cout,
    bf16_t* __restrict__ Qb, bf16_t* __restrict__ Kb, bf16_t* __restrict__ Vb,
    int M, int N, int K) {
  __shared__ bf16_t As[128 * 32];
  __shared__ bf16_t Bs[128 * 32];
  const int tid = threadIdx.x;
  const int wave = tid >> 6, lane = tid & 63, quad = lane >> 4, lr = lane & 15;
  const int bm = blockIdx.x * 128, bn = blockIdx.y * 128;
  const int wm = (wave >> 1) * 64, wn = (wave & 1) * 64;

  f32x4 acc[4][4] = {};

  const bf16_t* Ag;
  size_t strideA64;  // address delta for +64 rows
  if (MODE == 0) {
    Ag = A + (size_t)(bm + (tid >> 2)) * K + (tid & 3) * 8;
    strideA64 = (size_t)64 * K;
  } else {
    const int rr = bm + (tid >> 2);
    const int bidx = rr >> 10, seq = rr & 1023;
    Ag = A + ((size_t)bidx * 24 * 1024 + seq) * 32 + (tid & 3) * 8;
    strideA64 = (size_t)64 * 32;  // +64 seq rows, same batch
  }
  const bf16_t* Bg = Bw + (size_t)(bn + (tid >> 2)) * K + (tid & 3) * 8;
  bf16_t* As0 = As + tid * 8;
  bf16_t* Bs0 = Bs + tid * 8;
  const size_t strideB64 = (size_t)64 * K;

  for (int k0 = 0; k0 < K; k0 += 32) {
    const size_t aoff = (MODE == 0) ? (size_t)k0 : (size_t)(k0 >> 5) * 32768;
    __syncthreads();
    g2l16(Ag + aoff, As0);
    g2l16(Ag + strideA64 + aoff, As0 + 2048);
    g2l16(Bg + k0, Bs0);
    g2l16(Bg + strideB64 + k0, Bs0 + 2048);
    __syncthreads();
    bf16x8 af[4], bfr[4];
#pragma unroll
    for (int i = 0; i < 4; ++i)
      af[i] = *(const bf16x8*)(As + (wm + i * 16 + lr) * 32 + quad * 8);
#pragma unroll
    for (int j = 0; j < 4; ++j)
      bfr[j] = *(const bf16x8*)(Bs + (wn + j * 16 + lr) * 32 + quad * 8);
#pragma unroll
    for (int i = 0; i < 4; ++i)
#pragma unroll
      for (int j = 0; j < 4; ++j)
        acc[i][j] = MFMA16(af[i], bfr[j], acc[i][j]);
  }

#pragma unroll
  for (int i = 0; i < 4; ++i) {
    const int row = bm + wm + i * 16 + quad * 4;
#pragma unroll
    for (int j = 0; j < 4; ++j) {
      const int col = bn + wn + j * 16 + lr;
      const float bb = bias[col];
#pragma unroll
      for (int r = 0; r < 4; ++r) {
        const float v = acc[i][j][r] + bb;
        const int rr = row + r;
        if (MODE == 1) {
          Cout[(size_t)rr * N + col] = v;
        } else {
          const int b = rr >> 10, seq = rr & 1023;
          const int head = col / 96, w = col % 96;
          const int bh = b * 24 + head;
          if (w < 32) {
            Qb[((size_t)bh * 1024 + seq) * 32 + w] = (bf16_t)(v * 0.17677669529663687f);
          } else if (w < 64) {
            Kb[((size_t)bh * 1024 + seq) * 32 + (w - 32)] = (bf16_t)v;
          } else {
            Vb[((size_t)bh * 1024 + seq) * 32 + (w - 64)] = (bf16_t)v;
          }
        }
      }
    }
  }
}

// ---------------- flash attention v11: register double-buffered K/bias ----------------
// R1/R3 lesson: any launch-bound above 4 waves/EU spills (true per-wave reg
// use incl. MFMA accumulators ~120). Occupancy is NOT the lever; ILP is.
// v11 keeps (256,4) (the only non-spilling config) and explicitly
// software-pipelines across k-tiles: body t issues body t+1's K-fragment
// and bias loads FIRST, so their ~200-900cy latency hides under body t's
// MFMA + exp2 + LDS work. Explicit A/B register buffers (no runtime
// indexing -> no scratch). Row-sum stays on the MFMA pipe (R3-verified).
// exp2 via __builtin_amdgcn_exp2f = raw v_exp_f32.
__global__ __launch_bounds__(256, 4) void attn_flash(
    const bf16_t* __restrict__ Qb, const bf16_t* __restrict__ Kb,
    const bf16_t* __restrict__ Vtb, const bf16_t* __restrict__ relp,
    bf16_t* __restrict__ Ob) {
  __shared__ bf16_t Ps[4][16 * 132];

  const int tid = threadIdx.x;
  const int wave = tid >> 6, lane = tid & 63, quad = lane >> 4, lr = lane & 15;

  const int flat = blockIdx.x;
  const int xcd = flat & 7, slot = flat >> 3;
  const int pair = xcd + 8 * (slot >> 4);   // 0..191; same pair -> same XCD
  const int qi = slot & 15;
  const int b = pair / 24, h = pair % 24;
  const int bh = b * 24 + h;
  const int q0 = qi * 64 + wave * 16;
  const float LOG2E = 1.44269504f;

  const bf16x8 qf = *(const bf16x8*)(Qb + ((size_t)bh * 1024 + q0 + lr) * 32 + quad * 8);

  bf16x8 onesf;
#pragma unroll
  for (int i = 0; i < 8; ++i) onesf[i] = (bf16_t)1.0f;

  f32x4 o_acc[2] = {};
  f32x4 l_acc = {};  // row-sum accumulator: l = P * ones, same layout as o_acc

  // permuted bias: relp[((h*1024+q)*8 + kb)*128 + lr*8 + jt], k = kb*128+jt*16+lr
  const bf16_t* relg = relp + ((size_t)h * 1024 + q0 + quad * 4) * 1024 + lr * 8;
  const bf16_t* Kg = Kb + (size_t)bh * 1024 * 32;
  const bf16_t* Vg = Vtb + (size_t)bh * 32 * 1024;
  bf16_t* Pw = &Ps[wave][0];

  auto loadK = [&](int kt, bf16x8 (&kf)[8]) {
    const bf16_t* Kbase = Kg + (size_t)kt * 32;
#pragma unroll
    for (int jt = 0; jt < 8; ++jt)
      kf[jt] = *(const bf16x8*)(Kbase + (size_t)(jt * 16 + lr) * 32 + quad * 8);
  };
  auto loadB = [&](int kt, bf16x8 (&bw)[4]) {
    const bf16_t* rb = relg + kt;
#pragma unroll
    for (int r = 0; r < 4; ++r) bw[r] = *(const bf16x8*)(rb + (size_t)r * 1024);
  };

  // one k-tile: consume (kf,bw) for tile kt; prefetch tile ktn into (kfN,bwN)
  auto stage = [&](int kt, bf16x8 (&kf)[8], bf16x8 (&bw)[4],
                   int ktn, bf16x8 (&kfN)[8], bf16x8 (&bwN)[4], bool pre) {
    if (pre) {        // issue next tile's loads first -> latency hides under
      loadK(ktn, kfN);  // this tile's MFMA/exp2/LDS work
      loadB(ktn, bwN);
    }

    // S = Q K^T (C-layout: row = quad*4+r, col = jt*16+lr)
    f32x4 s[8];
    const f32x4 zz = {0.f, 0.f, 0.f, 0.f};
#pragma unroll
    for (int jt = 0; jt < 8; ++jt) s[jt] = MFMA16(qf, kf[jt], zz);

    // P = exp2(S*log2e + bias_prescaled) — no max subtraction needed
#pragma unroll
    for (int jt = 0; jt < 8; ++jt)
#pragma unroll
      for (int r = 0; r < 4; ++r)
        s[jt][r] = EXP2(fmaf(s[jt][r], LOG2E, (float)bw[r][jt]));

    // P -> LDS (C-layout to A-layout transform), per-wave region
#pragma unroll
    for (int jt = 0; jt < 8; ++jt)
#pragma unroll
      for (int r = 0; r < 4; ++r)
        Pw[(quad * 4 + r) * 132 + jt * 16 + lr] = (bf16_t)s[jt][r];

    // O += P V ; l += P * ones (row-sum on the MFMA pipe)
    const bf16_t* Vbase = Vg + kt;
#pragma unroll
    for (int ks = 0; ks < 4; ++ks) {
      const bf16x8 pf = *(const bf16x8*)(Pw + lr * 132 + ks * 32 + quad * 8);
      l_acc = MFMA16(pf, onesf, l_acc);
#pragma unroll
      for (int nt = 0; nt < 2; ++nt) {
        const bf16x8 vf = *(const bf16x8*)(Vbase + (size_t)(nt * 16 + lr) * 1024 + ks * 32 + quad * 8);
        o_acc[nt] = MFMA16(pf, vf, o_acc[nt]);
      }
    }
  };

  bf16x8 kfA[8], kfB[8], bwA[4], bwB[4];
  loadK(0, kfA);
  loadB(0, bwA);
  stage(0,   kfA, bwA, 128, kfB, bwB, true);
  stage(128, kfB, bwB, 256, kfA, bwA, true);
  stage(256, kfA, bwA, 384, kfB, bwB, true);
  stage(384, kfB, bwB, 512, kfA, bwA, true);
  stage(512, kfA, bwA, 640, kfB, bwB, true);
  stage(640, kfB, bwB, 768, kfA, bwA, true);
  stage(768, kfA, bwA, 896, kfB, bwB, true);
  stage(896, kfB, bwB, 0, kfA, bwA, false);

  // write O head-major [bh][seq][32] — packed stores
  float inv_l[4];
#pragma unroll
  for (int r = 0; r < 4; ++r) inv_l[r] = 1.0f / l_acc[r];
#pragma unroll
  for (int nt = 0; nt < 2; ++nt)
#pragma unroll
    for (int r = 0; r < 4; ++r) {
      const int seq = q0 + quad * 4 + r;
      Ob[((size_t)bh * 1024 + seq) * 32 + nt * 16 + lr] = (bf16_t)(o_acc[nt][r] * inv_l[r]);
    }
}

extern "C" void kernel_launch(void* const* d_in, const int* in_sizes, int n_in,
                              void* d_out, int out_size, void* d_ws, size_t ws_size,
                              hipStream_t stream) {
  const float* x = (const float*)d_in[0];
  const float* rel = (const float*)d_in[1];
  const float* Wqkv = (const float*)d_in[2];
  const float* bqkv = (const float*)d_in[3];
  const float* Wproj = (const float*)d_in[4];
  const float* bproj = (const float*)d_in[5];
  float* out = (float*)d_out;

  char* ws = (char*)d_ws;
  bf16_t* xb = (bf16_t*)ws;     ws += (size_t)8192 * 768 * 2;
  bf16_t* wqkvb = (bf16_t*)ws;  ws += (size_t)2304 * 768 * 2;
  bf16_t* wprojb = (bf16_t*)ws; ws += (size_t)768 * 768 * 2;
  bf16_t* Qb = (bf16_t*)ws;     ws += (size_t)192 * 1024 * 32 * 2;
  bf16_t* Kb = (bf16_t*)ws;     ws += (size_t)192 * 1024 * 32 * 2;
  bf16_t* Vb = (bf16_t*)ws;     ws += (size_t)192 * 1024 * 32 * 2;
  bf16_t* Vtb = (bf16_t*)ws;    ws += (size_t)192 * 1024 * 32 * 2;
  bf16_t* relp = (bf16_t*)ws;   ws += (size_t)24 * 1024 * 1024 * 2;
  bf16_t* Ob = xb;  // xb dead after QKV GEMM; O is head-major [bh][seq][32]

  cvt_f32_bf16<<<(8192 * 768 / 4 + 255) / 256, 256, 0, stream>>>(x, xb, 8192 * 768 / 4);
  cvt_f32_bf16<<<(2304 * 768 / 4 + 255) / 256, 256, 0, stream>>>(Wqkv, wqkvb, 2304 * 768 / 4);
  cvt_f32_bf16<<<(768 * 768 / 4 + 255) / 256, 256, 0, stream>>>(Wproj, wprojb, 768 * 768 / 4);
  permute_rel<<<dim3(24 * 1024), 256, 0, stream>>>(rel, relp);

  gemm_bt<0><<<dim3(64, 18), 256, 0, stream>>>(xb, wqkvb, bqkv, nullptr,
                                               Qb, Kb, Vb, 8192, 2304, 768);
  transpose_v<<<dim3(16, 192), 256, 0, stream>>>(Vb, Vtb);
  attn_flash<<<dim3(3072), 256, 0, stream>>>(Qb, Kb, Vtb, relp, Ob);
  gemm_bt<1><<<dim3(64, 6), 256, 0, stream>>>(Ob, wprojb, bproj, out,
                                              nullptr, nullptr, nullptr, 8192, 768, 768);
}

// Round 5
// 369.058 us; speedup vs baseline: 1.2213x; 1.1029x over previous
//
#include <hip/hip_runtime.h>

typedef __bf16 bf16_t;
typedef __bf16 bf16x8 __attribute__((ext_vector_type(8)));
typedef __bf16 bf16x4 __attribute__((ext_vector_type(4)));
typedef float f32x4 __attribute__((ext_vector_type(4)));

#define MFMA16(a, b, c) __builtin_amdgcn_mfma_f32_16x16x32_bf16(a, b, c, 0, 0, 0)

#if __has_builtin(__builtin_amdgcn_exp2f)
#define EXP2(x) __builtin_amdgcn_exp2f(x)
#else
#define EXP2(x) exp2f(x)
#endif

__device__ __forceinline__ void g2l16(const void* g, void* l) {
  __builtin_amdgcn_global_load_lds(
      (__attribute__((address_space(1))) void*)g,
      (__attribute__((address_space(3))) void*)l, 16, 0, 0);
}

// ---------------- fp32 -> bf16 conversion ----------------
__global__ void cvt_f32_bf16(const float* __restrict__ in, bf16_t* __restrict__ out, int n4) {
  int i = blockIdx.x * blockDim.x + threadIdx.x;
  if (i >= n4) return;
  const float4 v = ((const float4*)in)[i];
  bf16x4 o;
  o[0] = (bf16_t)v.x; o[1] = (bf16_t)v.y; o[2] = (bf16_t)v.z; o[3] = (bf16_t)v.w;
  ((bf16x4*)out)[i] = o;
}

// ---------------- bias permute: rel[h][q][k] f32 -> relp[h][q][kb][lr][jt] bf16 ----------------
// k = kb*128 + jt*16 + lr. Pre-scaled by log2e. One bf16x8 16B load per acc row.
__global__ void permute_rel(const float* __restrict__ rel, bf16_t* __restrict__ relp) {
  __shared__ float row[1024];
  const size_t base = (size_t)blockIdx.x * 1024;  // blockIdx.x = h*1024 + q
  const int t = threadIdx.x;
  *(float4*)(row + t * 4) = *(const float4*)(rel + base + t * 4);
  __syncthreads();
  const float LOG2E = 1.44269504f;
  const int o0 = t * 4;
  bf16x4 v;
#pragma unroll
  for (int j = 0; j < 4; ++j) {
    const int o = o0 + j;
    const int kb = o >> 7, rem = o & 127;
    const int lr = rem >> 3, jt = rem & 7;
    v[j] = (bf16_t)(row[kb * 128 + jt * 16 + lr] * LOG2E);
  }
  *(bf16x4*)(relp + base + o0) = v;
}

// ---------------- V transpose: [bh][seq][32] -> [bh][32][seq] ----------------
__global__ void transpose_v(const bf16_t* __restrict__ Vb, bf16_t* __restrict__ Vtb) {
  __shared__ bf16_t T[64][40];
  const int bh = blockIdx.y, s0 = blockIdx.x * 64;
  const int r = threadIdx.x >> 2, c8 = (threadIdx.x & 3) * 8;
  const bf16x8 v = *(const bf16x8*)(Vb + ((size_t)bh * 1024 + s0 + r) * 32 + c8);
#pragma unroll
  for (int j = 0; j < 8; ++j) T[r][c8 + j] = v[j];
  __syncthreads();
  const int d = threadIdx.x >> 3, q8 = (threadIdx.x & 7) * 8;
  bf16x8 o;
#pragma unroll
  for (int j = 0; j < 8; ++j) o[j] = T[q8 + j][d];
  *(bf16x8*)(Vtb + ((size_t)bh * 32 + d) * 1024 + s0 + q8) = o;
}

// ---------------- NT GEMM: C[m][n] = sum_k A[m][k] * B[n][k]  ----------------
// MODE 0: A row-major [M][K]; epilogue scatters to Q(scaled)/K/V bf16.
// MODE 1: A is head-major [B*24][1024][32] (attention O); fp32 C store.
template <int MODE>
__global__ __launch_bounds__(256, 2) void gemm_bt(
    const bf16_t* __restrict__ A, const bf16_t* __restrict__ Bw,
    const float* __restrict__ bias, float* __restrict__ Cout,
    bf16_t* __restrict__ Qb, bf16_t* __restrict__ Kb, bf16_t* __restrict__ Vb,
    int M, int N, int K) {
  __shared__ bf16_t As[128 * 32];
  __shared__ bf16_t Bs[128 * 32];
  const int tid = threadIdx.x;
  const int wave = tid >> 6, lane = tid & 63, quad = lane >> 4, lr = lane & 15;
  const int bm = blockIdx.x * 128, bn = blockIdx.y * 128;
  const int wm = (wave >> 1) * 64, wn = (wave & 1) * 64;

  f32x4 acc[4][4] = {};

  const bf16_t* Ag;
  size_t strideA64;  // address delta for +64 rows
  if (MODE == 0) {
    Ag = A + (size_t)(bm + (tid >> 2)) * K + (tid & 3) * 8;
    strideA64 = (size_t)64 * K;
  } else {
    const int rr = bm + (tid >> 2);
    const int bidx = rr >> 10, seq = rr & 1023;
    Ag = A + ((size_t)bidx * 24 * 1024 + seq) * 32 + (tid & 3) * 8;
    strideA64 = (size_t)64 * 32;  // +64 seq rows, same batch
  }
  const bf16_t* Bg = Bw + (size_t)(bn + (tid >> 2)) * K + (tid & 3) * 8;
  bf16_t* As0 = As + tid * 8;
  bf16_t* Bs0 = Bs + tid * 8;
  const size_t strideB64 = (size_t)64 * K;

  for (int k0 = 0; k0 < K; k0 += 32) {
    const size_t aoff = (MODE == 0) ? (size_t)k0 : (size_t)(k0 >> 5) * 32768;
    __syncthreads();
    g2l16(Ag + aoff, As0);
    g2l16(Ag + strideA64 + aoff, As0 + 2048);
    g2l16(Bg + k0, Bs0);
    g2l16(Bg + strideB64 + k0, Bs0 + 2048);
    __syncthreads();
    bf16x8 af[4], bfr[4];
#pragma unroll
    for (int i = 0; i < 4; ++i)
      af[i] = *(const bf16x8*)(As + (wm + i * 16 + lr) * 32 + quad * 8);
#pragma unroll
    for (int j = 0; j < 4; ++j)
      bfr[j] = *(const bf16x8*)(Bs + (wn + j * 16 + lr) * 32 + quad * 8);
#pragma unroll
    for (int i = 0; i < 4; ++i)
#pragma unroll
      for (int j = 0; j < 4; ++j)
        acc[i][j] = MFMA16(af[i], bfr[j], acc[i][j]);
  }

#pragma unroll
  for (int i = 0; i < 4; ++i) {
    const int row = bm + wm + i * 16 + quad * 4;
#pragma unroll
    for (int j = 0; j < 4; ++j) {
      const int col = bn + wn + j * 16 + lr;
      const float bb = bias[col];
#pragma unroll
      for (int r = 0; r < 4; ++r) {
        const float v = acc[i][j][r] + bb;
        const int rr = row + r;
        if (MODE == 1) {
          Cout[(size_t)rr * N + col] = v;
        } else {
          const int b = rr >> 10, seq = rr & 1023;
          const int head = col / 96, w = col % 96;
          const int bh = b * 24 + head;
          if (w < 32) {
            Qb[((size_t)bh * 1024 + seq) * 32 + w] = (bf16_t)(v * 0.17677669529663687f);
          } else if (w < 64) {
            Kb[((size_t)bh * 1024 + seq) * 32 + (w - 32)] = (bf16_t)v;
          } else {
            Vb[((size_t)bh * 1024 + seq) * 32 + (w - 64)] = (bf16_t)v;
          }
        }
      }
    }
  }
}

// ---------------- flash attention v12: LDS-staged K/V, 2-phase pipeline ----------------
// R4 lesson: source-level register prefetch got SUNK by the compiler
// (VGPR_Count=60 vs the ~110 the written code needs) -> K/V global latency
// still exposed, 168 TF = the documented 16x16-per-wave structural plateau.
// v12: block-level global_load_lds staging of K-tile (128x32) and Vt-tile
// (32x128) into double-buffered LDS (T3 minimum 2-phase recipe). DMA can't
// be sunk; __syncthreads() provides the vmcnt drain; all 4 waves share one
// staged copy (4x less L2 traffic); LDS read latency ~120cy vs global
// 300-900cy. g2l16 writes linearly, so the bank-conflict fix is the
// both-sides chunk-XOR swizzle (rule #21): pre-swizzled per-lane GLOBAL src
// + same XOR on the ds_read address.
//   K tile: chunk(row,c) c=0..3 (16B each); swz s=(row>>1)&3; 2/slot = free.
//   V tile: chunk(d,c)   c=0..15;           swz s=d&7;        2/slot = free.
// LDS: 2*8KB (K) + 2*8KB (V) + 16.9KB (Ps) = 49.7KB -> 3 blocks/CU.
__global__ __launch_bounds__(256, 4) void attn_flash(
    const bf16_t* __restrict__ Qb, const bf16_t* __restrict__ Kb,
    const bf16_t* __restrict__ Vtb, const bf16_t* __restrict__ relp,
    bf16_t* __restrict__ Ob) {
  __shared__ bf16_t Ks[2][128 * 32];
  __shared__ bf16_t Vs[2][32 * 128];
  __shared__ bf16_t Ps[4][16 * 132];

  const int tid = threadIdx.x;
  const int wave = tid >> 6, lane = tid & 63, quad = lane >> 4, lr = lane & 15;

  const int flat = blockIdx.x;
  const int xcd = flat & 7, slot = flat >> 3;
  const int pair = xcd + 8 * (slot >> 4);   // 0..191; same pair -> same XCD
  const int qi = slot & 15;
  const int b = pair / 24, h = pair % 24;
  const int bh = b * 24 + h;
  const int q0 = qi * 64 + wave * 16;
  const float LOG2E = 1.44269504f;

  const bf16x8 qf = *(const bf16x8*)(Qb + ((size_t)bh * 1024 + q0 + lr) * 32 + quad * 8);

  bf16x8 onesf;
#pragma unroll
  for (int i = 0; i < 8; ++i) onesf[i] = (bf16_t)1.0f;

  f32x4 o_acc[2] = {};
  f32x4 l_acc = {};  // row-sum accumulator: l = P * ones (MFMA pipe)

  // permuted bias: relp[((h*1024+q)*8 + kb)*128 + lr*8 + jt]
  const bf16_t* relg = relp + ((size_t)h * 1024 + q0 + quad * 4) * 1024 + lr * 8;
  const bf16_t* Kg = Kb + (size_t)bh * 1024 * 32;
  const bf16_t* Vg = Vtb + (size_t)bh * 32 * 1024;
  bf16_t* Pw = &Ps[wave][0];

  // stage K-tile + Vt-tile for k-window [kt, kt+128) into buffer sel
  auto stageKV = [&](int kt, int sel) {
#pragma unroll
    for (int p = 0; p < 2; ++p) {
      const int cid = p * 256 + tid;           // 0..511
      // K: row = cid>>2 (0..127), chunk c = cid&3; LDS slot c holds global chunk c^s(row)
      const int krow = cid >> 2, kc = cid & 3;
      const int ks_ = (krow >> 1) & 3;
      g2l16(Kg + ((size_t)(kt + krow) * 32 + ((kc ^ ks_) * 8)), &Ks[sel][cid * 8]);
      // V: d = cid>>4 (0..31), chunk c = cid&15
      const int vd = cid >> 4, vc = cid & 15;
      g2l16(Vg + ((size_t)vd * 1024 + kt + ((vc ^ (vd & 7)) * 8)), &Vs[sel][cid * 8]);
    }
  };

  auto body = [&](int kt, int sel) {
    // bias tile: one bf16x8 per acc row (already scaled by log2e)
    bf16x8 bw[4];
    const bf16_t* rb = relg + kt;
#pragma unroll
    for (int r = 0; r < 4; ++r) bw[r] = *(const bf16x8*)(rb + (size_t)r * 1024);

    // S = Q K^T from staged K (swizzled read)
    f32x4 s[8];
    const f32x4 zz = {0.f, 0.f, 0.f, 0.f};
    const int kcs = quad ^ ((lr >> 1) & 3);   // swizzled chunk, constant per lane
#pragma unroll
    for (int jt = 0; jt < 8; ++jt) {
      const int row = jt * 16 + lr;
      const bf16x8 kf = *(const bf16x8*)&Ks[sel][row * 32 + kcs * 8];
      s[jt] = MFMA16(qf, kf, zz);
    }
    // P = exp2(S*log2e + bias_prescaled)
#pragma unroll
    for (int jt = 0; jt < 8; ++jt)
#pragma unroll
      for (int r = 0; r < 4; ++r)
        s[jt][r] = EXP2(fmaf(s[jt][r], LOG2E, (float)bw[r][jt]));

    // P -> LDS (C-layout to A-layout transform), per-wave region
#pragma unroll
    for (int jt = 0; jt < 8; ++jt)
#pragma unroll
      for (int r = 0; r < 4; ++r)
        Pw[(quad * 4 + r) * 132 + jt * 16 + lr] = (bf16_t)s[jt][r];

    // O += P V ; l += P * ones — V from staged LDS (swizzled read)
#pragma unroll
    for (int ks = 0; ks < 4; ++ks) {
      const bf16x8 pf = *(const bf16x8*)(Pw + lr * 132 + ks * 32 + quad * 8);
      l_acc = MFMA16(pf, onesf, l_acc);
#pragma unroll
      for (int nt = 0; nt < 2; ++nt) {
        const int d = nt * 16 + lr;
        const int vc = (ks * 4 + quad) ^ (d & 7);
        const bf16x8 vf = *(const bf16x8*)&Vs[sel][d * 128 + vc * 8];
        o_acc[nt] = MFMA16(pf, vf, o_acc[nt]);
      }
    }
  };

  stageKV(0, 0);
  __syncthreads();  // drains staging vmcnt (compiler emits full waitcnt)
  for (int t = 0; t < 8; ++t) {
    const int sel = t & 1;
    if (t < 7) stageKV((t + 1) * 128, sel ^ 1);  // prefetch next tile
    body(t * 128, sel);                          // compute current tile
    __syncthreads();  // drain staging + release buffer sel for t+2
  }

  // write O head-major [bh][seq][32] — packed stores
  float inv_l[4];
#pragma unroll
  for (int r = 0; r < 4; ++r) inv_l[r] = 1.0f / l_acc[r];
#pragma unroll
  for (int nt = 0; nt < 2; ++nt)
#pragma unroll
    for (int r = 0; r < 4; ++r) {
      const int seq = q0 + quad * 4 + r;
      Ob[((size_t)bh * 1024 + seq) * 32 + nt * 16 + lr] = (bf16_t)(o_acc[nt][r] * inv_l[r]);
    }
}

extern "C" void kernel_launch(void* const* d_in, const int* in_sizes, int n_in,
                              void* d_out, int out_size, void* d_ws, size_t ws_size,
                              hipStream_t stream) {
  const float* x = (const float*)d_in[0];
  const float* rel = (const float*)d_in[1];
  const float* Wqkv = (const float*)d_in[2];
  const float* bqkv = (const float*)d_in[3];
  const float* Wproj = (const float*)d_in[4];
  const float* bproj = (const float*)d_in[5];
  float* out = (float*)d_out;

  char* ws = (char*)d_ws;
  bf16_t* xb = (bf16_t*)ws;     ws += (size_t)8192 * 768 * 2;
  bf16_t* wqkvb = (bf16_t*)ws;  ws += (size_t)2304 * 768 * 2;
  bf16_t* wprojb = (bf16_t*)ws; ws += (size_t)768 * 768 * 2;
  bf16_t* Qb = (bf16_t*)ws;     ws += (size_t)192 * 1024 * 32 * 2;
  bf16_t* Kb = (bf16_t*)ws;     ws += (size_t)192 * 1024 * 32 * 2;
  bf16_t* Vb = (bf16_t*)ws;     ws += (size_t)192 * 1024 * 32 * 2;
  bf16_t* Vtb = (bf16_t*)ws;    ws += (size_t)192 * 1024 * 32 * 2;
  bf16_t* relp = (bf16_t*)ws;   ws += (size_t)24 * 1024 * 1024 * 2;
  bf16_t* Ob = xb;  // xb dead after QKV GEMM; O is head-major [bh][seq][32]

  cvt_f32_bf16<<<(8192 * 768 / 4 + 255) / 256, 256, 0, stream>>>(x, xb, 8192 * 768 / 4);
  cvt_f32_bf16<<<(2304 * 768 / 4 + 255) / 256, 256, 0, stream>>>(Wqkv, wqkvb, 2304 * 768 / 4);
  cvt_f32_bf16<<<(768 * 768 / 4 + 255) / 256, 256, 0, stream>>>(Wproj, wprojb, 768 * 768 / 4);
  permute_rel<<<dim3(24 * 1024), 256, 0, stream>>>(rel, relp);

  gemm_bt<0><<<dim3(64, 18), 256, 0, stream>>>(xb, wqkvb, bqkv, nullptr,
                                               Qb, Kb, Vb, 8192, 2304, 768);
  transpose_v<<<dim3(16, 192), 256, 0, stream>>>(Vb, Vtb);
  attn_flash<<<dim3(3072), 256, 0, stream>>>(Qb, Kb, Vtb, relp, Ob);
  gemm_bt<1><<<dim3(64, 6), 256, 0, stream>>>(Ob, wprojb, bproj, out,
                                              nullptr, nullptr, nullptr, 8192, 768, 768);
}

// Round 6
// 355.053 us; speedup vs baseline: 1.2695x; 1.0394x over previous
//
#include <hip/hip_runtime.h>

typedef __bf16 bf16_t;
typedef __bf16 bf16x8 __attribute__((ext_vector_type(8)));
typedef __bf16 bf16x4 __attribute__((ext_vector_type(4)));
typedef float f32x4 __attribute__((ext_vector_type(4)));

#define MFMA16(a, b, c) __builtin_amdgcn_mfma_f32_16x16x32_bf16(a, b, c, 0, 0, 0)

#if __has_builtin(__builtin_amdgcn_exp2f)
#define EXP2(x) __builtin_amdgcn_exp2f(x)
#else
#define EXP2(x) exp2f(x)
#endif

__device__ __forceinline__ void g2l16(const void* g, void* l) {
  __builtin_amdgcn_global_load_lds(
      (__attribute__((address_space(1))) void*)g,
      (__attribute__((address_space(3))) void*)l, 16, 0, 0);
}

// ---------------- fp32 -> bf16 conversion ----------------
__global__ void cvt_f32_bf16(const float* __restrict__ in, bf16_t* __restrict__ out, int n4) {
  int i = blockIdx.x * blockDim.x + threadIdx.x;
  if (i >= n4) return;
  const float4 v = ((const float4*)in)[i];
  bf16x4 o;
  o[0] = (bf16_t)v.x; o[1] = (bf16_t)v.y; o[2] = (bf16_t)v.z; o[3] = (bf16_t)v.w;
  ((bf16x4*)out)[i] = o;
}

// ---------------- bias permute v2 (for swapped-QK attn) ----------------
// attn lane (lr,quad) of wave handling q-tile qt, window kb needs
//   bias[q = qt*16+lr][k = kb*128 + (2i+(j>>2))*16 + quad*4 + (j&3)]
// stored at relp[(h*64+qt)*16384 + kb*2048 + i*512 + lane*8 + j]  (prescaled
// by log2e, bf16). Each attn bias load = 64 lanes x 16B = 1KB contiguous.
__global__ void permute_rel(const float* __restrict__ rel, bf16_t* __restrict__ relp) {
  __shared__ bf16_t Tl[16][1032];
  const int blk = blockIdx.x;            // h*64 + qt
  const int h = blk >> 6, qt = blk & 63;
  const int t = threadIdx.x;
  const float LOG2E = 1.44269504f;
  const float* src = rel + ((size_t)h * 1024 + qt * 16) * 1024;
#pragma unroll
  for (int it = 0; it < 16; ++it) {
    const int fid = it * 256 + t;        // float4 index 0..4095
    const int row = fid >> 8, c4 = (fid & 255) * 4;
    const float4 v = *(const float4*)(src + (size_t)row * 1024 + c4);
    bf16x4 o;
    o[0] = (bf16_t)(v.x * LOG2E); o[1] = (bf16_t)(v.y * LOG2E);
    o[2] = (bf16_t)(v.z * LOG2E); o[3] = (bf16_t)(v.w * LOG2E);
    *(bf16x4*)&Tl[row][c4] = o;
  }
  __syncthreads();
  bf16_t* dst = relp + (size_t)blk * 16384;
#pragma unroll
  for (int s = 0; s < 8; ++s) {
    const int c = s * 256 + t;           // bf16x8-chunk 0..2047
    const int kb = c >> 8, i = (c >> 6) & 3, lane = c & 63;
    const int lr = lane & 15, quad = lane >> 4;
    bf16x8 o;
#pragma unroll
    for (int j = 0; j < 8; ++j) {
      const int k = kb * 128 + (2 * i + (j >> 2)) * 16 + quad * 4 + (j & 3);
      o[j] = Tl[lr][k];
    }
    *(bf16x8*)(dst + (size_t)c * 8) = o;
  }
}

// ---------------- V transpose: [bh][seq][32] -> [bh][32][seq] ----------------
__global__ void transpose_v(const bf16_t* __restrict__ Vb, bf16_t* __restrict__ Vtb) {
  __shared__ bf16_t T[64][40];
  const int bh = blockIdx.y, s0 = blockIdx.x * 64;
  const int r = threadIdx.x >> 2, c8 = (threadIdx.x & 3) * 8;
  const bf16x8 v = *(const bf16x8*)(Vb + ((size_t)bh * 1024 + s0 + r) * 32 + c8);
#pragma unroll
  for (int j = 0; j < 8; ++j) T[r][c8 + j] = v[j];
  __syncthreads();
  const int d = threadIdx.x >> 3, q8 = (threadIdx.x & 7) * 8;
  bf16x8 o;
#pragma unroll
  for (int j = 0; j < 8; ++j) o[j] = T[q8 + j][d];
  *(bf16x8*)(Vtb + ((size_t)bh * 32 + d) * 1024 + s0 + q8) = o;
}

// ---------------- NT GEMM: C[m][n] = sum_k A[m][k] * B[n][k]  ----------------
// MODE 0: A row-major [M][K]; epilogue scatters to Q(scaled)/K/V bf16.
// MODE 1: A is head-major [B*24][1024][32] (attention O); fp32 C store.
template <int MODE>
__global__ __launch_bounds__(256, 2) void gemm_bt(
    const bf16_t* __restrict__ A, const bf16_t* __restrict__ Bw,
    const float* __restrict__ bias, float* __restrict__ Cout,
    bf16_t* __restrict__ Qb, bf16_t* __restrict__ Kb, bf16_t* __restrict__ Vb,
    int M, int N, int K) {
  __shared__ bf16_t As[128 * 32];
  __shared__ bf16_t Bs[128 * 32];
  const int tid = threadIdx.x;
  const int wave = tid >> 6, lane = tid & 63, quad = lane >> 4, lr = lane & 15;
  const int bm = blockIdx.x * 128, bn = blockIdx.y * 128;
  const int wm = (wave >> 1) * 64, wn = (wave & 1) * 64;

  f32x4 acc[4][4] = {};

  const bf16_t* Ag;
  size_t strideA64;  // address delta for +64 rows
  if (MODE == 0) {
    Ag = A + (size_t)(bm + (tid >> 2)) * K + (tid & 3) * 8;
    strideA64 = (size_t)64 * K;
  } else {
    const int rr = bm + (tid >> 2);
    const int bidx = rr >> 10, seq = rr & 1023;
    Ag = A + ((size_t)bidx * 24 * 1024 + seq) * 32 + (tid & 3) * 8;
    strideA64 = (size_t)64 * 32;  // +64 seq rows, same batch
  }
  const bf16_t* Bg = Bw + (size_t)(bn + (tid >> 2)) * K + (tid & 3) * 8;
  bf16_t* As0 = As + tid * 8;
  bf16_t* Bs0 = Bs + tid * 8;
  const size_t strideB64 = (size_t)64 * K;

  for (int k0 = 0; k0 < K; k0 += 32) {
    const size_t aoff = (MODE == 0) ? (size_t)k0 : (size_t)(k0 >> 5) * 32768;
    __syncthreads();
    g2l16(Ag + aoff, As0);
    g2l16(Ag + strideA64 + aoff, As0 + 2048);
    g2l16(Bg + k0, Bs0);
    g2l16(Bg + strideB64 + k0, Bs0 + 2048);
    __syncthreads();
    bf16x8 af[4], bfr[4];
#pragma unroll
    for (int i = 0; i < 4; ++i)
      af[i] = *(const bf16x8*)(As + (wm + i * 16 + lr) * 32 + quad * 8);
#pragma unroll
    for (int j = 0; j < 4; ++j)
      bfr[j] = *(const bf16x8*)(Bs + (wn + j * 16 + lr) * 32 + quad * 8);
#pragma unroll
    for (int i = 0; i < 4; ++i)
#pragma unroll
      for (int j = 0; j < 4; ++j)
        acc[i][j] = MFMA16(af[i], bfr[j], acc[i][j]);
  }

#pragma unroll
  for (int i = 0; i < 4; ++i) {
    const int row = bm + wm + i * 16 + quad * 4;
#pragma unroll
    for (int j = 0; j < 4; ++j) {
      const int col = bn + wn + j * 16 + lr;
      const float bb = bias[col];
#pragma unroll
      for (int r = 0; r < 4; ++r) {
        const float v = acc[i][j][r] + bb;
        const int rr = row + r;
        if (MODE == 1) {
          Cout[(size_t)rr * N + col] = v;
        } else {
          const int b = rr >> 10, seq = rr & 1023;
          const int head = col / 96, w = col % 96;
          const int bh = b * 24 + head;
          if (w < 32) {
            Qb[((size_t)bh * 1024 + seq) * 32 + w] = (bf16_t)(v * 0.17677669529663687f);
          } else if (w < 64) {
            Kb[((size_t)bh * 1024 + seq) * 32 + (w - 32)] = (bf16_t)v;
          } else {
            Vb[((size_t)bh * 1024 + seq) * 32 + (w - 64)] = (bf16_t)v;
          }
        }
      }
    }
  }
}

// ---------------- flash attention v13: swapped QK^T + packed P ----------------
// R5 residual: VALU 38 / MFMA 11 / 50% issue-idle; 32 scalar ds_write_b16
// per body (C->A layout transform) ~190cy of LDS issue + lgkm serialization.
// v13 computes S^T = MFMA(kf, qf) (operands swapped): lane then holds 4
// accumulator values at CONTIGUOUS k (q = lr, k = jt*16+quad*4+r), so the
// P store becomes 8x ds_write_b64 (packed bf16x4) -> 4x fewer LDS ops.
// Bias is re-permuted to match (permute_rel v2); each bias load is now 1KB
// fully contiguous per wave. PV read / l=P*ones / O epilogue layouts are
// unchanged (D row = quad*4+r = q, col = lr).
// LDS: 2x8KB (K) + 2x8KB (V) + 4x16x136x2 (P) = 50.2KB -> 3 blocks/CU.
__global__ __launch_bounds__(256, 4) void attn_flash(
    const bf16_t* __restrict__ Qb, const bf16_t* __restrict__ Kb,
    const bf16_t* __restrict__ Vtb, const bf16_t* __restrict__ relp,
    bf16_t* __restrict__ Ob) {
  __shared__ bf16_t Ks[2][128 * 32];
  __shared__ bf16_t Vs[2][32 * 128];
  __shared__ bf16_t Ps[4][16 * 136];

  const int tid = threadIdx.x;
  const int wave = tid >> 6, lane = tid & 63, quad = lane >> 4, lr = lane & 15;

  const int flat = blockIdx.x;
  const int xcd = flat & 7, slot = flat >> 3;
  const int pair = xcd + 8 * (slot >> 4);   // 0..191; same pair -> same XCD
  const int qi = slot & 15;
  const int b = pair / 24, h = pair % 24;
  const int bh = b * 24 + h;
  const int q0 = qi * 64 + wave * 16;
  const float LOG2E = 1.44269504f;

  const bf16x8 qf = *(const bf16x8*)(Qb + ((size_t)bh * 1024 + q0 + lr) * 32 + quad * 8);

  bf16x8 onesf;
#pragma unroll
  for (int i = 0; i < 8; ++i) onesf[i] = (bf16_t)1.0f;

  f32x4 o_acc[2] = {};
  f32x4 l_acc = {};  // row-sum accumulator: l = P * ones (MFMA pipe)

  // permuted bias v2: block = h*64 + (qi*4 + wave); per-lane 4x bf16x8
  const bf16_t* relg = relp + (size_t)(h * 64 + qi * 4 + wave) * 16384 + lane * 8;
  const bf16_t* Kg = Kb + (size_t)bh * 1024 * 32;
  const bf16_t* Vg = Vtb + (size_t)bh * 32 * 1024;
  bf16_t* Pw = &Ps[wave][0];

  // stage K-tile + Vt-tile for k-window [kt, kt+128) into buffer sel
  auto stageKV = [&](int kt, int sel) {
#pragma unroll
    for (int p = 0; p < 2; ++p) {
      const int cid = p * 256 + tid;           // 0..511
      // K: row = cid>>2 (0..127), chunk c = cid&3; LDS slot c holds global chunk c^s(row)
      const int krow = cid >> 2, kc = cid & 3;
      const int ks_ = (krow >> 1) & 3;
      g2l16(Kg + ((size_t)(kt + krow) * 32 + ((kc ^ ks_) * 8)), &Ks[sel][cid * 8]);
      // V: d = cid>>4 (0..31), chunk c = cid&15
      const int vd = cid >> 4, vc = cid & 15;
      g2l16(Vg + ((size_t)vd * 1024 + kt + ((vc ^ (vd & 7)) * 8)), &Vs[sel][cid * 8]);
    }
  };

  auto body = [&](int kt, int sel) {
    // bias tile: 4x bf16x8, 1KB contiguous per wave-load
    bf16x8 bb[4];
    const bf16_t* rb = relg + (size_t)(kt >> 7) * 2048;
#pragma unroll
    for (int i = 0; i < 4; ++i) bb[i] = *(const bf16x8*)(rb + i * 512);

    // S^T = K Q^T (swapped): lane holds q = lr, k = jt*16 + quad*4 + r
    f32x4 s[8];
    const f32x4 zz = {0.f, 0.f, 0.f, 0.f};
    const int kcs = quad ^ ((lr >> 1) & 3);   // staged-K chunk swizzle
#pragma unroll
    for (int jt = 0; jt < 8; ++jt) {
      const bf16x8 kf = *(const bf16x8*)&Ks[sel][(jt * 16 + lr) * 32 + kcs * 8];
      s[jt] = MFMA16(kf, qf, zz);
    }
    // P = exp2(S*log2e + bias_prescaled); bias (jt,r) = bb[jt>>1][(jt&1)*4+r]
#pragma unroll
    for (int jt = 0; jt < 8; ++jt)
#pragma unroll
      for (int r = 0; r < 4; ++r)
        s[jt][r] = EXP2(fmaf(s[jt][r], LOG2E, (float)bb[jt >> 1][(jt & 1) * 4 + r]));

    // P -> LDS: packed b64, row q = lr, cols jt*16 + quad*4 .. +3
#pragma unroll
    for (int jt = 0; jt < 8; ++jt) {
      bf16x4 p4;
      p4[0] = (bf16_t)s[jt][0]; p4[1] = (bf16_t)s[jt][1];
      p4[2] = (bf16_t)s[jt][2]; p4[3] = (bf16_t)s[jt][3];
      *(bf16x4*)&Pw[lr * 136 + jt * 16 + quad * 4] = p4;
    }

    // O += P V ; l += P * ones — pf is 16B contiguous row-read
    const bf16_t* Vbase = Vg + kt;
#pragma unroll
    for (int ks = 0; ks < 4; ++ks) {
      const bf16x8 pf = *(const bf16x8*)&Pw[lr * 136 + ks * 32 + quad * 8];
      l_acc = MFMA16(pf, onesf, l_acc);
#pragma unroll
      for (int nt = 0; nt < 2; ++nt) {
        const int d = nt * 16 + lr;
        const int vc = (ks * 4 + quad) ^ (d & 7);
        const bf16x8 vf = *(const bf16x8*)&Vs[sel][d * 128 + vc * 8];
        o_acc[nt] = MFMA16(pf, vf, o_acc[nt]);
      }
    }
  };

  stageKV(0, 0);
  __syncthreads();  // drains staging vmcnt
  for (int t = 0; t < 8; ++t) {
    const int sel = t & 1;
    if (t < 7) stageKV((t + 1) * 128, sel ^ 1);  // prefetch next tile
    body(t * 128, sel);                          // compute current tile
    __syncthreads();
  }

  // write O head-major [bh][seq][32] — packed stores
  float inv_l[4];
#pragma unroll
  for (int r = 0; r < 4; ++r) inv_l[r] = 1.0f / l_acc[r];
#pragma unroll
  for (int nt = 0; nt < 2; ++nt)
#pragma unroll
    for (int r = 0; r < 4; ++r) {
      const int seq = q0 + quad * 4 + r;
      Ob[((size_t)bh * 1024 + seq) * 32 + nt * 16 + lr] = (bf16_t)(o_acc[nt][r] * inv_l[r]);
    }
}

extern "C" void kernel_launch(void* const* d_in, const int* in_sizes, int n_in,
                              void* d_out, int out_size, void* d_ws, size_t ws_size,
                              hipStream_t stream) {
  const float* x = (const float*)d_in[0];
  const float* rel = (const float*)d_in[1];
  const float* Wqkv = (const float*)d_in[2];
  const float* bqkv = (const float*)d_in[3];
  const float* Wproj = (const float*)d_in[4];
  const float* bproj = (const float*)d_in[5];
  float* out = (float*)d_out;

  char* ws = (char*)d_ws;
  bf16_t* xb = (bf16_t*)ws;     ws += (size_t)8192 * 768 * 2;
  bf16_t* wqkvb = (bf16_t*)ws;  ws += (size_t)2304 * 768 * 2;
  bf16_t* wprojb = (bf16_t*)ws; ws += (size_t)768 * 768 * 2;
  bf16_t* Qb = (bf16_t*)ws;     ws += (size_t)192 * 1024 * 32 * 2;
  bf16_t* Kb = (bf16_t*)ws;     ws += (size_t)192 * 1024 * 32 * 2;
  bf16_t* Vb = (bf16_t*)ws;     ws += (size_t)192 * 1024 * 32 * 2;
  bf16_t* Vtb = (bf16_t*)ws;    ws += (size_t)192 * 1024 * 32 * 2;
  bf16_t* relp = (bf16_t*)ws;   ws += (size_t)24 * 1024 * 1024 * 2;
  bf16_t* Ob = xb;  // xb dead after QKV GEMM; O is head-major [bh][seq][32]

  cvt_f32_bf16<<<(8192 * 768 / 4 + 255) / 256, 256, 0, stream>>>(x, xb, 8192 * 768 / 4);
  cvt_f32_bf16<<<(2304 * 768 / 4 + 255) / 256, 256, 0, stream>>>(Wqkv, wqkvb, 2304 * 768 / 4);
  cvt_f32_bf16<<<(768 * 768 / 4 + 255) / 256, 256, 0, stream>>>(Wproj, wprojb, 768 * 768 / 4);
  permute_rel<<<dim3(24 * 64), 256, 0, stream>>>(rel, relp);

  gemm_bt<0><<<dim3(64, 18), 256, 0, stream>>>(xb, wqkvb, bqkv, nullptr,
                                               Qb, Kb, Vb, 8192, 2304, 768);
  transpose_v<<<dim3(16, 192), 256, 0, stream>>>(Vb, Vtb);
  attn_flash<<<dim3(3072), 256, 0, stream>>>(Qb, Kb, Vtb, relp, Ob);
  gemm_bt<1><<<dim3(64, 6), 256, 0, stream>>>(Ob, wprojb, bproj, out,
                                              nullptr, nullptr, nullptr, 8192, 768, 768);
}

// Round 8
// 332.465 us; speedup vs baseline: 1.3558x; 1.0679x over previous
//
#include <hip/hip_runtime.h>

typedef __bf16 bf16_t;
typedef __bf16 bf16x8 __attribute__((ext_vector_type(8)));
typedef __bf16 bf16x4 __attribute__((ext_vector_type(4)));
typedef float f32x4 __attribute__((ext_vector_type(4)));
typedef unsigned int u32;
typedef u32 u32x2 __attribute__((ext_vector_type(2)));
typedef u32 u32x4 __attribute__((ext_vector_type(4)));

#define MFMA16(a, b, c) __builtin_amdgcn_mfma_f32_16x16x32_bf16(a, b, c, 0, 0, 0)

#if __has_builtin(__builtin_amdgcn_exp2f)
#define EXP2(x) __builtin_amdgcn_exp2f(x)
#else
#define EXP2(x) exp2f(x)
#endif

// Combined 4x4 quad-transpose step on a dword pair.
// Builtin convention (pinned by the m214-verified attn kernel):
//   {r0, r1} = permlaneN_swap(a, b)  ->  r0 = [a_low, b_low], r1 = [a_high, b_high]
// (R7's raw asm with vdst=a, src=b produced the REVERSED hardware convention
//  and failed absmax 0.035; the compiler's intrinsic mapping handles it.)
#if __has_builtin(__builtin_amdgcn_permlane32_swap) && __has_builtin(__builtin_amdgcn_permlane16_swap)
#define PERMSWAP(a, b)                                                     \
  do {                                                                     \
    u32x2 _r = __builtin_amdgcn_permlane32_swap((a), (b), false, false);   \
    u32x2 _s = __builtin_amdgcn_permlane16_swap(_r[0], _r[1], false, false); \
    (a) = _s[0];                                                           \
    (b) = _s[1];                                                           \
  } while (0)
#else
// Fallback: reversed-operand raw asm (omega-convention fix from the R7 trace)
#define PERMSWAP(a, b)                                                     \
  do {                                                                     \
    asm("v_permlane32_swap_b32 %0, %1" : "+v"(b), "+v"(a));                \
    asm("v_permlane16_swap_b32 %0, %1" : "+v"(b), "+v"(a));                \
  } while (0)
#endif

__device__ __forceinline__ void g2l16(const void* g, void* l) {
  __builtin_amdgcn_global_load_lds(
      (__attribute__((address_space(1))) void*)g,
      (__attribute__((address_space(3))) void*)l, 16, 0, 0);
}

// ---------------- fp32 -> bf16 conversion ----------------
__global__ void cvt_f32_bf16(const float* __restrict__ in, bf16_t* __restrict__ out, int n4) {
  int i = blockIdx.x * blockDim.x + threadIdx.x;
  if (i >= n4) return;
  const float4 v = ((const float4*)in)[i];
  bf16x4 o;
  o[0] = (bf16_t)v.x; o[1] = (bf16_t)v.y; o[2] = (bf16_t)v.z; o[3] = (bf16_t)v.w;
  ((bf16x4*)out)[i] = o;
}

// ---------------- bias permute v2 (for swapped-QK attn) ----------------
// attn lane (lr,quad) of wave handling q-tile qt, window kb needs
//   bias[q = qt*16+lr][k = kb*128 + (2i+(j>>2))*16 + quad*4 + (j&3)]
// stored at relp[(h*64+qt)*16384 + kb*2048 + i*512 + lane*8 + j]  (prescaled
// by log2e, bf16). Each attn bias load = 64 lanes x 16B = 1KB contiguous.
__global__ void permute_rel(const float* __restrict__ rel, bf16_t* __restrict__ relp) {
  __shared__ bf16_t Tl[16][1032];
  const int blk = blockIdx.x;            // h*64 + qt
  const int h = blk >> 6, qt = blk & 63;
  const int t = threadIdx.x;
  const float LOG2E = 1.44269504f;
  const float* src = rel + ((size_t)h * 1024 + qt * 16) * 1024;
#pragma unroll
  for (int it = 0; it < 16; ++it) {
    const int fid = it * 256 + t;        // float4 index 0..4095
    const int row = fid >> 8, c4 = (fid & 255) * 4;
    const float4 v = *(const float4*)(src + (size_t)row * 1024 + c4);
    bf16x4 o;
    o[0] = (bf16_t)(v.x * LOG2E); o[1] = (bf16_t)(v.y * LOG2E);
    o[2] = (bf16_t)(v.z * LOG2E); o[3] = (bf16_t)(v.w * LOG2E);
    *(bf16x4*)&Tl[row][c4] = o;
  }
  __syncthreads();
  bf16_t* dst = relp + (size_t)blk * 16384;
#pragma unroll
  for (int s = 0; s < 8; ++s) {
    const int c = s * 256 + t;           // bf16x8-chunk 0..2047
    const int kb = c >> 8, i = (c >> 6) & 3, lane = c & 63;
    const int lr = lane & 15, quad = lane >> 4;
    bf16x8 o;
#pragma unroll
    for (int j = 0; j < 8; ++j) {
      const int k = kb * 128 + (2 * i + (j >> 2)) * 16 + quad * 4 + (j & 3);
      o[j] = Tl[lr][k];
    }
    *(bf16x8*)(dst + (size_t)c * 8) = o;
  }
}

// ---------------- V transpose: [bh][seq][32] -> [bh][32][seq] ----------------
__global__ void transpose_v(const bf16_t* __restrict__ Vb, bf16_t* __restrict__ Vtb) {
  __shared__ bf16_t T[64][40];
  const int bh = blockIdx.y, s0 = blockIdx.x * 64;
  const int r = threadIdx.x >> 2, c8 = (threadIdx.x & 3) * 8;
  const bf16x8 v = *(const bf16x8*)(Vb + ((size_t)bh * 1024 + s0 + r) * 32 + c8);
#pragma unroll
  for (int j = 0; j < 8; ++j) T[r][c8 + j] = v[j];
  __syncthreads();
  const int d = threadIdx.x >> 3, q8 = (threadIdx.x & 7) * 8;
  bf16x8 o;
#pragma unroll
  for (int j = 0; j < 8; ++j) o[j] = T[q8 + j][d];
  *(bf16x8*)(Vtb + ((size_t)bh * 32 + d) * 1024 + s0 + q8) = o;
}

// ---------------- NT GEMM: C[m][n] = sum_k A[m][k] * B[n][k]  ----------------
// MODE 0: A row-major [M][K]; epilogue scatters to Q(scaled)/K/V bf16.
// MODE 1: A is head-major [B*24][1024][32] (attention O); fp32 C store.
template <int MODE>
__global__ __launch_bounds__(256, 2) void gemm_bt(
    const bf16_t* __restrict__ A, const bf16_t* __restrict__ Bw,
    const float* __restrict__ bias, float* __restrict__ Cout,
    bf16_t* __restrict__ Qb, bf16_t* __restrict__ Kb, bf16_t* __restrict__ Vb,
    int M, int N, int K) {
  __shared__ bf16_t As[128 * 32];
  __shared__ bf16_t Bs[128 * 32];
  const int tid = threadIdx.x;
  const int wave = tid >> 6, lane = tid & 63, quad = lane >> 4, lr = lane & 15;
  const int bm = blockIdx.x * 128, bn = blockIdx.y * 128;
  const int wm = (wave >> 1) * 64, wn = (wave & 1) * 64;

  f32x4 acc[4][4] = {};

  const bf16_t* Ag;
  size_t strideA64;  // address delta for +64 rows
  if (MODE == 0) {
    Ag = A + (size_t)(bm + (tid >> 2)) * K + (tid & 3) * 8;
    strideA64 = (size_t)64 * K;
  } else {
    const int rr = bm + (tid >> 2);
    const int bidx = rr >> 10, seq = rr & 1023;
    Ag = A + ((size_t)bidx * 24 * 1024 + seq) * 32 + (tid & 3) * 8;
    strideA64 = (size_t)64 * 32;  // +64 seq rows, same batch
  }
  const bf16_t* Bg = Bw + (size_t)(bn + (tid >> 2)) * K + (tid & 3) * 8;
  bf16_t* As0 = As + tid * 8;
  bf16_t* Bs0 = Bs + tid * 8;
  const size_t strideB64 = (size_t)64 * K;

  for (int k0 = 0; k0 < K; k0 += 32) {
    const size_t aoff = (MODE == 0) ? (size_t)k0 : (size_t)(k0 >> 5) * 32768;
    __syncthreads();
    g2l16(Ag + aoff, As0);
    g2l16(Ag + strideA64 + aoff, As0 + 2048);
    g2l16(Bg + k0, Bs0);
    g2l16(Bg + strideB64 + k0, Bs0 + 2048);
    __syncthreads();
    bf16x8 af[4], bfr[4];
#pragma unroll
    for (int i = 0; i < 4; ++i)
      af[i] = *(const bf16x8*)(As + (wm + i * 16 + lr) * 32 + quad * 8);
#pragma unroll
    for (int j = 0; j < 4; ++j)
      bfr[j] = *(const bf16x8*)(Bs + (wn + j * 16 + lr) * 32 + quad * 8);
#pragma unroll
    for (int i = 0; i < 4; ++i)
#pragma unroll
      for (int j = 0; j < 4; ++j)
        acc[i][j] = MFMA16(af[i], bfr[j], acc[i][j]);
  }

#pragma unroll
  for (int i = 0; i < 4; ++i) {
    const int row = bm + wm + i * 16 + quad * 4;
#pragma unroll
    for (int j = 0; j < 4; ++j) {
      const int col = bn + wn + j * 16 + lr;
      const float bb = bias[col];
#pragma unroll
      for (int r = 0; r < 4; ++r) {
        const float v = acc[i][j][r] + bb;
        const int rr = row + r;
        if (MODE == 1) {
          Cout[(size_t)rr * N + col] = v;
        } else {
          const int b = rr >> 10, seq = rr & 1023;
          const int head = col / 96, w = col % 96;
          const int bh = b * 24 + head;
          if (w < 32) {
            Qb[((size_t)bh * 1024 + seq) * 32 + w] = (bf16_t)(v * 0.17677669529663687f);
          } else if (w < 64) {
            Kb[((size_t)bh * 1024 + seq) * 32 + (w - 32)] = (bf16_t)v;
          } else {
            Vb[((size_t)bh * 1024 + seq) * 32 + (w - 64)] = (bf16_t)v;
          }
        }
      }
    }
  }
}

// ---------------- flash attention v15: in-register P via permlane (builtin) ----------------
// Same structure as R7: swapped QK^T leaves lane (lr,quad) holding
// P[q=lr][k=jt*16+quad*4+r]; the PV A-frag needs k = ks*32+quad*8+j — a 4x4
// transpose across quads. Per dword pair (d0 = k%32 in quad*4+{0,1} group,
// d2 = +16 group): PERMSWAP(d0,d2) yields d0 = A-frag dword0 (k=quad*8+{0,1})
// and d2 = dword2 (k=quad*8+{4,5}); same for (d1,d3). Trace:
//   [E0 E1 E2 E3],[O0 O1 O2 O3] -swap32-> [E0 E1 O0 O1],[E2 E3 O2 O3]
//                                -swap16-> [E0 E2 O0 O2],[E1 E3 O1 O3]  = f0,f2
// Removes the P LDS round trip (8 ds_write_b64 + 4 ds_read_b128 + lgkm wait
// per body) and the 17.4KB Ps array: LDS 50.2 -> 32KB -> 4 blocks/CU.
__global__ __launch_bounds__(256, 4) void attn_flash(
    const bf16_t* __restrict__ Qb, const bf16_t* __restrict__ Kb,
    const bf16_t* __restrict__ Vtb, const bf16_t* __restrict__ relp,
    bf16_t* __restrict__ Ob) {
  __shared__ bf16_t Ks[2][128 * 32];
  __shared__ bf16_t Vs[2][32 * 128];

  const int tid = threadIdx.x;
  const int wave = tid >> 6, lane = tid & 63, quad = lane >> 4, lr = lane & 15;

  const int flat = blockIdx.x;
  const int xcd = flat & 7, slot = flat >> 3;
  const int pair = xcd + 8 * (slot >> 4);   // 0..191; same pair -> same XCD
  const int qi = slot & 15;
  const int b = pair / 24, h = pair % 24;
  const int bh = b * 24 + h;
  const int q0 = qi * 64 + wave * 16;
  const float LOG2E = 1.44269504f;

  const bf16x8 qf = *(const bf16x8*)(Qb + ((size_t)bh * 1024 + q0 + lr) * 32 + quad * 8);

  bf16x8 onesf;
#pragma unroll
  for (int i = 0; i < 8; ++i) onesf[i] = (bf16_t)1.0f;

  f32x4 o_acc[2] = {};
  f32x4 l_acc = {};  // row-sum accumulator: l = P * ones (MFMA pipe)

  // permuted bias v2: block = h*64 + (qi*4 + wave); per-lane 4x bf16x8
  const bf16_t* relg = relp + (size_t)(h * 64 + qi * 4 + wave) * 16384 + lane * 8;
  const bf16_t* Kg = Kb + (size_t)bh * 1024 * 32;
  const bf16_t* Vg = Vtb + (size_t)bh * 32 * 1024;

  // stage K-tile + Vt-tile for k-window [kt, kt+128) into buffer sel
  auto stageKV = [&](int kt, int sel) {
#pragma unroll
    for (int p = 0; p < 2; ++p) {
      const int cid = p * 256 + tid;           // 0..511
      // K: row = cid>>2 (0..127), chunk c = cid&3; LDS slot c holds global chunk c^s(row)
      const int krow = cid >> 2, kc = cid & 3;
      const int ks_ = (krow >> 1) & 3;
      g2l16(Kg + ((size_t)(kt + krow) * 32 + ((kc ^ ks_) * 8)), &Ks[sel][cid * 8]);
      // V: d = cid>>4 (0..31), chunk c = cid&15
      const int vd = cid >> 4, vc = cid & 15;
      g2l16(Vg + ((size_t)vd * 1024 + kt + ((vc ^ (vd & 7)) * 8)), &Vs[sel][cid * 8]);
    }
  };

  auto body = [&](int kt, int sel) {
    // bias tile: 4x bf16x8, 1KB contiguous per wave-load
    bf16x8 bb[4];
    const bf16_t* rb = relg + (size_t)(kt >> 7) * 2048;
#pragma unroll
    for (int i = 0; i < 4; ++i) bb[i] = *(const bf16x8*)(rb + i * 512);

    // S^T = K Q^T (swapped): lane holds q = lr, k = jt*16 + quad*4 + r
    f32x4 s[8];
    const f32x4 zz = {0.f, 0.f, 0.f, 0.f};
    const int kcs = quad ^ ((lr >> 1) & 3);   // staged-K chunk swizzle
#pragma unroll
    for (int jt = 0; jt < 8; ++jt) {
      const bf16x8 kf = *(const bf16x8*)&Ks[sel][(jt * 16 + lr) * 32 + kcs * 8];
      s[jt] = MFMA16(kf, qf, zz);
    }
    // P = exp2(S*log2e + bias_prescaled); bias (jt,r) = bb[jt>>1][(jt&1)*4+r]
#pragma unroll
    for (int jt = 0; jt < 8; ++jt)
#pragma unroll
      for (int r = 0; r < 4; ++r)
        s[jt][r] = EXP2(fmaf(s[jt][r], LOG2E, (float)bb[jt >> 1][(jt & 1) * 4 + r]));

    // P -> PV A-frag entirely in registers (permlane 4x4 quad-transpose)
#pragma unroll
    for (int ks = 0; ks < 4; ++ks) {
      bf16x4 pe, po;
#pragma unroll
      for (int r = 0; r < 4; ++r) {
        pe[r] = (bf16_t)s[2 * ks][r];
        po[r] = (bf16_t)s[2 * ks + 1][r];
      }
      u32x2 ue = __builtin_bit_cast(u32x2, pe);
      u32x2 uo = __builtin_bit_cast(u32x2, po);
      u32 d0 = ue[0], d1 = ue[1], d2 = uo[0], d3 = uo[1];
      PERMSWAP(d0, d2);
      PERMSWAP(d1, d3);
      u32x4 uf = {d0, d1, d2, d3};
      const bf16x8 pf = __builtin_bit_cast(bf16x8, uf);

      l_acc = MFMA16(pf, onesf, l_acc);
#pragma unroll
      for (int nt = 0; nt < 2; ++nt) {
        const int d = nt * 16 + lr;
        const int vc = (ks * 4 + quad) ^ (d & 7);
        const bf16x8 vf = *(const bf16x8*)&Vs[sel][d * 128 + vc * 8];
        o_acc[nt] = MFMA16(pf, vf, o_acc[nt]);
      }
    }
  };

  stageKV(0, 0);
  __syncthreads();  // drains staging vmcnt
  for (int t = 0; t < 8; ++t) {
    const int sel = t & 1;
    if (t < 7) stageKV((t + 1) * 128, sel ^ 1);  // prefetch next tile
    body(t * 128, sel);                          // compute current tile
    __syncthreads();
  }

  // write O head-major [bh][seq][32] — packed stores
  float inv_l[4];
#pragma unroll
  for (int r = 0; r < 4; ++r) inv_l[r] = 1.0f / l_acc[r];
#pragma unroll
  for (int nt = 0; nt < 2; ++nt)
#pragma unroll
    for (int r = 0; r < 4; ++r) {
      const int seq = q0 + quad * 4 + r;
      Ob[((size_t)bh * 1024 + seq) * 32 + nt * 16 + lr] = (bf16_t)(o_acc[nt][r] * inv_l[r]);
    }
}

extern "C" void kernel_launch(void* const* d_in, const int* in_sizes, int n_in,
                              void* d_out, int out_size, void* d_ws, size_t ws_size,
                              hipStream_t stream) {
  const float* x = (const float*)d_in[0];
  const float* rel = (const float*)d_in[1];
  const float* Wqkv = (const float*)d_in[2];
  const float* bqkv = (const float*)d_in[3];
  const float* Wproj = (const float*)d_in[4];
  const float* bproj = (const float*)d_in[5];
  float* out = (float*)d_out;

  char* ws = (char*)d_ws;
  bf16_t* xb = (bf16_t*)ws;     ws += (size_t)8192 * 768 * 2;
  bf16_t* wqkvb = (bf16_t*)ws;  ws += (size_t)2304 * 768 * 2;
  bf16_t* wprojb = (bf16_t*)ws; ws += (size_t)768 * 768 * 2;
  bf16_t* Qb = (bf16_t*)ws;     ws += (size_t)192 * 1024 * 32 * 2;
  bf16_t* Kb = (bf16_t*)ws;     ws += (size_t)192 * 1024 * 32 * 2;
  bf16_t* Vb = (bf16_t*)ws;     ws += (size_t)192 * 1024 * 32 * 2;
  bf16_t* Vtb = (bf16_t*)ws;    ws += (size_t)192 * 1024 * 32 * 2;
  bf16_t* relp = (bf16_t*)ws;   ws += (size_t)24 * 1024 * 1024 * 2;
  bf16_t* Ob = xb;  // xb dead after QKV GEMM; O is head-major [bh][seq][32]

  cvt_f32_bf16<<<(8192 * 768 / 4 + 255) / 256, 256, 0, stream>>>(x, xb, 8192 * 768 / 4);
  cvt_f32_bf16<<<(2304 * 768 / 4 + 255) / 256, 256, 0, stream>>>(Wqkv, wqkvb, 2304 * 768 / 4);
  cvt_f32_bf16<<<(768 * 768 / 4 + 255) / 256, 256, 0, stream>>>(Wproj, wprojb, 768 * 768 / 4);
  permute_rel<<<dim3(24 * 64), 256, 0, stream>>>(rel, relp);

  gemm_bt<0><<<dim3(64, 18), 256, 0, stream>>>(xb, wqkvb, bqkv, nullptr,
                                               Qb, Kb, Vb, 8192, 2304, 768);
  transpose_v<<<dim3(16, 192), 256, 0, stream>>>(Vb, Vtb);
  attn_flash<<<dim3(3072), 256, 0, stream>>>(Qb, Kb, Vtb, relp, Ob);
  gemm_bt<1><<<dim3(64, 6), 256, 0, stream>>>(Ob, wprojb, bproj, out,
                                              nullptr, nullptr, nullptr, 8192, 768, 768);
}

// Round 9
// 331.663 us; speedup vs baseline: 1.3591x; 1.0024x over previous
//
#include <hip/hip_runtime.h>

typedef __bf16 bf16_t;
typedef __bf16 bf16x8 __attribute__((ext_vector_type(8)));
typedef __bf16 bf16x4 __attribute__((ext_vector_type(4)));
typedef float f32x4 __attribute__((ext_vector_type(4)));
typedef unsigned int u32;
typedef u32 u32x2 __attribute__((ext_vector_type(2)));
typedef u32 u32x4 __attribute__((ext_vector_type(4)));

#define MFMA16(a, b, c) __builtin_amdgcn_mfma_f32_16x16x32_bf16(a, b, c, 0, 0, 0)

#if __has_builtin(__builtin_amdgcn_exp2f)
#define EXP2(x) __builtin_amdgcn_exp2f(x)
#else
#define EXP2(x) exp2f(x)
#endif

// Combined 4x4 quad-transpose step on a dword pair (R8-verified builtin path).
#if __has_builtin(__builtin_amdgcn_permlane32_swap) && __has_builtin(__builtin_amdgcn_permlane16_swap)
#define PERMSWAP(a, b)                                                     \
  do {                                                                     \
    u32x2 _r = __builtin_amdgcn_permlane32_swap((a), (b), false, false);   \
    u32x2 _s = __builtin_amdgcn_permlane16_swap(_r[0], _r[1], false, false); \
    (a) = _s[0];                                                           \
    (b) = _s[1];                                                           \
  } while (0)
#else
#define PERMSWAP(a, b)                                                     \
  do {                                                                     \
    asm("v_permlane32_swap_b32 %0, %1" : "+v"(b), "+v"(a));                \
    asm("v_permlane16_swap_b32 %0, %1" : "+v"(b), "+v"(a));                \
  } while (0)
#endif

__device__ __forceinline__ void g2l16(const void* g, void* l) {
  __builtin_amdgcn_global_load_lds(
      (__attribute__((address_space(1))) void*)g,
      (__attribute__((address_space(3))) void*)l, 16, 0, 0);
}

// ---------------- fp32 -> bf16 conversion ----------------
__global__ void cvt_f32_bf16(const float* __restrict__ in, bf16_t* __restrict__ out, int n4) {
  int i = blockIdx.x * blockDim.x + threadIdx.x;
  if (i >= n4) return;
  const float4 v = ((const float4*)in)[i];
  bf16x4 o;
  o[0] = (bf16_t)v.x; o[1] = (bf16_t)v.y; o[2] = (bf16_t)v.z; o[3] = (bf16_t)v.w;
  ((bf16x4*)out)[i] = o;
}

// ---------------- bias permute v2 (for swapped-QK attn) ----------------
// attn lane (lr,quad) of wave handling q-tile qt, window kb needs
//   bias[q = qt*16+lr][k = kb*128 + (2i+(j>>2))*16 + quad*4 + (j&3)]
// stored at relp[(h*64+qt)*16384 + kb*2048 + i*512 + lane*8 + j]  (prescaled
// by log2e, bf16). Each attn bias load = 64 lanes x 16B = 1KB contiguous.
__global__ void permute_rel(const float* __restrict__ rel, bf16_t* __restrict__ relp) {
  __shared__ bf16_t Tl[16][1032];
  const int blk = blockIdx.x;            // h*64 + qt
  const int h = blk >> 6, qt = blk & 63;
  const int t = threadIdx.x;
  const float LOG2E = 1.44269504f;
  const float* src = rel + ((size_t)h * 1024 + qt * 16) * 1024;
#pragma unroll
  for (int it = 0; it < 16; ++it) {
    const int fid = it * 256 + t;        // float4 index 0..4095
    const int row = fid >> 8, c4 = (fid & 255) * 4;
    const float4 v = *(const float4*)(src + (size_t)row * 1024 + c4);
    bf16x4 o;
    o[0] = (bf16_t)(v.x * LOG2E); o[1] = (bf16_t)(v.y * LOG2E);
    o[2] = (bf16_t)(v.z * LOG2E); o[3] = (bf16_t)(v.w * LOG2E);
    *(bf16x4*)&Tl[row][c4] = o;
  }
  __syncthreads();
  bf16_t* dst = relp + (size_t)blk * 16384;
#pragma unroll
  for (int s = 0; s < 8; ++s) {
    const int c = s * 256 + t;           // bf16x8-chunk 0..2047
    const int kb = c >> 8, i = (c >> 6) & 3, lane = c & 63;
    const int lr = lane & 15, quad = lane >> 4;
    bf16x8 o;
#pragma unroll
    for (int j = 0; j < 8; ++j) {
      const int k = kb * 128 + (2 * i + (j >> 2)) * 16 + quad * 4 + (j & 3);
      o[j] = Tl[lr][k];
    }
    *(bf16x8*)(dst + (size_t)c * 8) = o;
  }
}

// ---------------- V transpose: [bh][seq][32] -> [bh][32][seq] ----------------
__global__ void transpose_v(const bf16_t* __restrict__ Vb, bf16_t* __restrict__ Vtb) {
  __shared__ bf16_t T[64][40];
  const int bh = blockIdx.y, s0 = blockIdx.x * 64;
  const int r = threadIdx.x >> 2, c8 = (threadIdx.x & 3) * 8;
  const bf16x8 v = *(const bf16x8*)(Vb + ((size_t)bh * 1024 + s0 + r) * 32 + c8);
#pragma unroll
  for (int j = 0; j < 8; ++j) T[r][c8 + j] = v[j];
  __syncthreads();
  const int d = threadIdx.x >> 3, q8 = (threadIdx.x & 7) * 8;
  bf16x8 o;
#pragma unroll
  for (int j = 0; j < 8; ++j) o[j] = T[q8 + j][d];
  *(bf16x8*)(Vtb + ((size_t)bh * 32 + d) * 1024 + s0 + q8) = o;
}

// ---------------- NT GEMM v2: 2-phase double-buffered staging ----------------
// R9: the old loop (sync -> issue g2l16 -> sync -> compute) exposed the full
// ~500cy staging latency on every one of the K/32 steps, with only 2 blocks/CU
// to mask it. Port the attn R5 pattern: double-buffer LDS, issue tile t+1's
// stage BEFORE computing tile t, ONE barrier per iteration (drains next tile's
// vmcnt + protects buffer reuse: sel read at t, restaged at t+2 — barrier at
// end of t+1 separates them). LDS 4x8KB = 32KB, still 2 blocks/CU at (256,2).
// MODE 0: A row-major [M][K]; epilogue scatters to Q(scaled)/K/V bf16.
// MODE 1: A is head-major [B*24][1024][32] (attention O); fp32 C store.
template <int MODE>
__global__ __launch_bounds__(256, 2) void gemm_bt(
    const bf16_t* __restrict__ A, const bf16_t* __restrict__ Bw,
    const float* __restrict__ bias, float* __restrict__ Cout,
    bf16_t* __restrict__ Qb, bf16_t* __restrict__ Kb, bf16_t* __restrict__ Vb,
    int M, int N, int K) {
  __shared__ bf16_t As[2][128 * 32];
  __shared__ bf16_t Bs[2][128 * 32];
  const int tid = threadIdx.x;
  const int wave = tid >> 6, lane = tid & 63, quad = lane >> 4, lr = lane & 15;
  const int bm = blockIdx.x * 128, bn = blockIdx.y * 128;
  const int wm = (wave >> 1) * 64, wn = (wave & 1) * 64;

  f32x4 acc[4][4] = {};

  const bf16_t* Ag;
  size_t strideA64;  // address delta for +64 rows
  if (MODE == 0) {
    Ag = A + (size_t)(bm + (tid >> 2)) * K + (tid & 3) * 8;
    strideA64 = (size_t)64 * K;
  } else {
    const int rr = bm + (tid >> 2);
    const int bidx = rr >> 10, seq = rr & 1023;
    Ag = A + ((size_t)bidx * 24 * 1024 + seq) * 32 + (tid & 3) * 8;
    strideA64 = (size_t)64 * 32;  // +64 seq rows, same batch
  }
  const bf16_t* Bg = Bw + (size_t)(bn + (tid >> 2)) * K + (tid & 3) * 8;
  const size_t strideB64 = (size_t)64 * K;

  auto stage = [&](int k0, int sel) {
    const size_t aoff = (MODE == 0) ? (size_t)k0 : (size_t)(k0 >> 5) * 32768;
    g2l16(Ag + aoff, &As[sel][tid * 8]);
    g2l16(Ag + strideA64 + aoff, &As[sel][tid * 8 + 2048]);
    g2l16(Bg + k0, &Bs[sel][tid * 8]);
    g2l16(Bg + strideB64 + k0, &Bs[sel][tid * 8 + 2048]);
  };

  const int NT = K >> 5;
  stage(0, 0);
  __syncthreads();  // drain initial staging
  for (int t = 0; t < NT; ++t) {
    const int sel = t & 1;
    if (t + 1 < NT) stage((t + 1) * 32, sel ^ 1);  // prefetch next K-step
    bf16x8 af[4], bfr[4];
#pragma unroll
    for (int i = 0; i < 4; ++i)
      af[i] = *(const bf16x8*)(&As[sel][(wm + i * 16 + lr) * 32 + quad * 8]);
#pragma unroll
    for (int j = 0; j < 4; ++j)
      bfr[j] = *(const bf16x8*)(&Bs[sel][(wn + j * 16 + lr) * 32 + quad * 8]);
#pragma unroll
    for (int i = 0; i < 4; ++i)
#pragma unroll
      for (int j = 0; j < 4; ++j)
        acc[i][j] = MFMA16(af[i], bfr[j], acc[i][j]);
    __syncthreads();  // drains prefetch vmcnt + this tile's lgkm; releases sel
  }

#pragma unroll
  for (int i = 0; i < 4; ++i) {
    const int row = bm + wm + i * 16 + quad * 4;
#pragma unroll
    for (int j = 0; j < 4; ++j) {
      const int col = bn + wn + j * 16 + lr;
      const float bb = bias[col];
#pragma unroll
      for (int r = 0; r < 4; ++r) {
        const float v = acc[i][j][r] + bb;
        const int rr = row + r;
        if (MODE == 1) {
          Cout[(size_t)rr * N + col] = v;
        } else {
          const int b = rr >> 10, seq = rr & 1023;
          const int head = col / 96, w = col % 96;
          const int bh = b * 24 + head;
          if (w < 32) {
            Qb[((size_t)bh * 1024 + seq) * 32 + w] = (bf16_t)(v * 0.17677669529663687f);
          } else if (w < 64) {
            Kb[((size_t)bh * 1024 + seq) * 32 + (w - 32)] = (bf16_t)v;
          } else {
            Vb[((size_t)bh * 1024 + seq) * 32 + (w - 64)] = (bf16_t)v;
          }
        }
      }
    }
  }
}

// ---------------- flash attention v15 (R8-verified, unchanged) ----------------
__global__ __launch_bounds__(256, 4) void attn_flash(
    const bf16_t* __restrict__ Qb, const bf16_t* __restrict__ Kb,
    const bf16_t* __restrict__ Vtb, const bf16_t* __restrict__ relp,
    bf16_t* __restrict__ Ob) {
  __shared__ bf16_t Ks[2][128 * 32];
  __shared__ bf16_t Vs[2][32 * 128];

  const int tid = threadIdx.x;
  const int wave = tid >> 6, lane = tid & 63, quad = lane >> 4, lr = lane & 15;

  const int flat = blockIdx.x;
  const int xcd = flat & 7, slot = flat >> 3;
  const int pair = xcd + 8 * (slot >> 4);   // 0..191; same pair -> same XCD
  const int qi = slot & 15;
  const int b = pair / 24, h = pair % 24;
  const int bh = b * 24 + h;
  const int q0 = qi * 64 + wave * 16;
  const float LOG2E = 1.44269504f;

  const bf16x8 qf = *(const bf16x8*)(Qb + ((size_t)bh * 1024 + q0 + lr) * 32 + quad * 8);

  bf16x8 onesf;
#pragma unroll
  for (int i = 0; i < 8; ++i) onesf[i] = (bf16_t)1.0f;

  f32x4 o_acc[2] = {};
  f32x4 l_acc = {};  // row-sum accumulator: l = P * ones (MFMA pipe)

  // permuted bias v2: block = h*64 + (qi*4 + wave); per-lane 4x bf16x8
  const bf16_t* relg = relp + (size_t)(h * 64 + qi * 4 + wave) * 16384 + lane * 8;
  const bf16_t* Kg = Kb + (size_t)bh * 1024 * 32;
  const bf16_t* Vg = Vtb + (size_t)bh * 32 * 1024;

  // stage K-tile + Vt-tile for k-window [kt, kt+128) into buffer sel
  auto stageKV = [&](int kt, int sel) {
#pragma unroll
    for (int p = 0; p < 2; ++p) {
      const int cid = p * 256 + tid;           // 0..511
      const int krow = cid >> 2, kc = cid & 3;
      const int ks_ = (krow >> 1) & 3;
      g2l16(Kg + ((size_t)(kt + krow) * 32 + ((kc ^ ks_) * 8)), &Ks[sel][cid * 8]);
      const int vd = cid >> 4, vc = cid & 15;
      g2l16(Vg + ((size_t)vd * 1024 + kt + ((vc ^ (vd & 7)) * 8)), &Vs[sel][cid * 8]);
    }
  };

  auto body = [&](int kt, int sel) {
    // bias tile: 4x bf16x8, 1KB contiguous per wave-load
    bf16x8 bb[4];
    const bf16_t* rb = relg + (size_t)(kt >> 7) * 2048;
#pragma unroll
    for (int i = 0; i < 4; ++i) bb[i] = *(const bf16x8*)(rb + i * 512);

    // S^T = K Q^T (swapped): lane holds q = lr, k = jt*16 + quad*4 + r
    f32x4 s[8];
    const f32x4 zz = {0.f, 0.f, 0.f, 0.f};
    const int kcs = quad ^ ((lr >> 1) & 3);   // staged-K chunk swizzle
#pragma unroll
    for (int jt = 0; jt < 8; ++jt) {
      const bf16x8 kf = *(const bf16x8*)&Ks[sel][(jt * 16 + lr) * 32 + kcs * 8];
      s[jt] = MFMA16(kf, qf, zz);
    }
    // P = exp2(S*log2e + bias_prescaled); bias (jt,r) = bb[jt>>1][(jt&1)*4+r]
#pragma unroll
    for (int jt = 0; jt < 8; ++jt)
#pragma unroll
      for (int r = 0; r < 4; ++r)
        s[jt][r] = EXP2(fmaf(s[jt][r], LOG2E, (float)bb[jt >> 1][(jt & 1) * 4 + r]));

    // P -> PV A-frag entirely in registers (permlane 4x4 quad-transpose)
#pragma unroll
    for (int ks = 0; ks < 4; ++ks) {
      bf16x4 pe, po;
#pragma unroll
      for (int r = 0; r < 4; ++r) {
        pe[r] = (bf16_t)s[2 * ks][r];
        po[r] = (bf16_t)s[2 * ks + 1][r];
      }
      u32x2 ue = __builtin_bit_cast(u32x2, pe);
      u32x2 uo = __builtin_bit_cast(u32x2, po);
      u32 d0 = ue[0], d1 = ue[1], d2 = uo[0], d3 = uo[1];
      PERMSWAP(d0, d2);
      PERMSWAP(d1, d3);
      u32x4 uf = {d0, d1, d2, d3};
      const bf16x8 pf = __builtin_bit_cast(bf16x8, uf);

      l_acc = MFMA16(pf, onesf, l_acc);
#pragma unroll
      for (int nt = 0; nt < 2; ++nt) {
        const int d = nt * 16 + lr;
        const int vc = (ks * 4 + quad) ^ (d & 7);
        const bf16x8 vf = *(const bf16x8*)&Vs[sel][d * 128 + vc * 8];
        o_acc[nt] = MFMA16(pf, vf, o_acc[nt]);
      }
    }
  };

  stageKV(0, 0);
  __syncthreads();  // drains staging vmcnt
  for (int t = 0; t < 8; ++t) {
    const int sel = t & 1;
    if (t < 7) stageKV((t + 1) * 128, sel ^ 1);  // prefetch next tile
    body(t * 128, sel);                          // compute current tile
    __syncthreads();
  }

  // write O head-major [bh][seq][32] — packed stores
  float inv_l[4];
#pragma unroll
  for (int r = 0; r < 4; ++r) inv_l[r] = 1.0f / l_acc[r];
#pragma unroll
  for (int nt = 0; nt < 2; ++nt)
#pragma unroll
    for (int r = 0; r < 4; ++r) {
      const int seq = q0 + quad * 4 + r;
      Ob[((size_t)bh * 1024 + seq) * 32 + nt * 16 + lr] = (bf16_t)(o_acc[nt][r] * inv_l[r]);
    }
}

extern "C" void kernel_launch(void* const* d_in, const int* in_sizes, int n_in,
                              void* d_out, int out_size, void* d_ws, size_t ws_size,
                              hipStream_t stream) {
  const float* x = (const float*)d_in[0];
  const float* rel = (const float*)d_in[1];
  const float* Wqkv = (const float*)d_in[2];
  const float* bqkv = (const float*)d_in[3];
  const float* Wproj = (const float*)d_in[4];
  const float* bproj = (const float*)d_in[5];
  float* out = (float*)d_out;

  char* ws = (char*)d_ws;
  bf16_t* xb = (bf16_t*)ws;     ws += (size_t)8192 * 768 * 2;
  bf16_t* wqkvb = (bf16_t*)ws;  ws += (size_t)2304 * 768 * 2;
  bf16_t* wprojb = (bf16_t*)ws; ws += (size_t)768 * 768 * 2;
  bf16_t* Qb = (bf16_t*)ws;     ws += (size_t)192 * 1024 * 32 * 2;
  bf16_t* Kb = (bf16_t*)ws;     ws += (size_t)192 * 1024 * 32 * 2;
  bf16_t* Vb = (bf16_t*)ws;     ws += (size_t)192 * 1024 * 32 * 2;
  bf16_t* Vtb = (bf16_t*)ws;    ws += (size_t)192 * 1024 * 32 * 2;
  bf16_t* relp = (bf16_t*)ws;   ws += (size_t)24 * 1024 * 1024 * 2;
  bf16_t* Ob = xb;  // xb dead after QKV GEMM; O is head-major [bh][seq][32]

  cvt_f32_bf16<<<(8192 * 768 / 4 + 255) / 256, 256, 0, stream>>>(x, xb, 8192 * 768 / 4);
  cvt_f32_bf16<<<(2304 * 768 / 4 + 255) / 256, 256, 0, stream>>>(Wqkv, wqkvb, 2304 * 768 / 4);
  cvt_f32_bf16<<<(768 * 768 / 4 + 255) / 256, 256, 0, stream>>>(Wproj, wprojb, 768 * 768 / 4);
  permute_rel<<<dim3(24 * 64), 256, 0, stream>>>(rel, relp);

  gemm_bt<0><<<dim3(64, 18), 256, 0, stream>>>(xb, wqkvb, bqkv, nullptr,
                                               Qb, Kb, Vb, 8192, 2304, 768);
  transpose_v<<<dim3(16, 192), 256, 0, stream>>>(Vb, Vtb);
  attn_flash<<<dim3(3072), 256, 0, stream>>>(Qb, Kb, Vtb, relp, Ob);
  gemm_bt<1><<<dim3(64, 6), 256, 0, stream>>>(Ob, wprojb, bproj, out,
                                              nullptr, nullptr, nullptr, 8192, 768, 768);
}